// Round 2
// baseline (1133.004 us; speedup 1.0000x reference)
//
#include <hip/hip_runtime.h>

// ---------------- problem constants ----------------
#define BATCH 2
#define SEQ   2048
#define DIM   1024
#define NH    16
#define DK    64
#define LWIN  256
#define GSTR  64
#define GCNT  32      // SEQ/GSTR
#define SWHALF 256    // SW/2
#define SCALE_F 0.125f
#define NEG_INF -1e30f

typedef __attribute__((ext_vector_type(4))) float f4;
typedef __attribute__((ext_vector_type(4))) float f32x4;
typedef __attribute__((ext_vector_type(8))) short s16x8;
typedef __attribute__((ext_vector_type(4))) int  i32x4;
typedef __attribute__((ext_vector_type(4))) unsigned short u16x4;

__device__ __forceinline__ float bf2f(unsigned short u){ return __uint_as_float(((unsigned)u) << 16); }
__device__ __forceinline__ unsigned short f2bf(float f){
  unsigned u = __float_as_uint(f);
  u += 0x7FFFu + ((u >> 16) & 1u);
  return (unsigned short)(u >> 16);
}

// ---------------- cast fp32 -> bf16 (vectorized) ----------------
__global__ __launch_bounds__(256) void cast_bf16_kernel(const float* __restrict__ in,
                                                        unsigned short* __restrict__ out, int n){
  int i = (blockIdx.x * 256 + threadIdx.x) * 4;
  if (i < n){
    f4 v = *(const f4*)&in[i];
    u16x4 o = { f2bf(v[0]), f2bf(v[1]), f2bf(v[2]), f2bf(v[3]) };
    *(u16x4*)&out[i] = o;
  }
}

// ---------------- transpose + cast: W (K x N fp32) -> Wt (N x K bf16) ----------------
__global__ __launch_bounds__(256) void transpose_cast(const float* __restrict__ W,
                                                      unsigned short* __restrict__ Wt,
                                                      int K, int N){
  __shared__ float tile[32][33];
  int x = threadIdx.x & 31, y = threadIdx.x >> 5;
  int bc = blockIdx.x << 5;   // over N
  int br = blockIdx.y << 5;   // over K
  #pragma unroll
  for (int yy = y; yy < 32; yy += 8)
    tile[yy][x] = W[(size_t)(br + yy) * N + bc + x];
  __syncthreads();
  #pragma unroll
  for (int yy = y; yy < 32; yy += 8)
    Wt[(size_t)(bc + yy) * K + br + x] = f2bf(tile[x][yy]);
}

// ---------------- gc extraction: x[:, ::64] -> bf16, padded to 128 rows ----------------
__global__ __launch_bounds__(256) void gc_extract(const float* __restrict__ x,
                                                  unsigned short* __restrict__ gcb){
  int row = blockIdx.x;         // 0..127
  int t = threadIdx.x;          // 256 threads * 4 elems
  unsigned short* dst = gcb + (size_t)row * DIM;
  if (row < BATCH * GCNT){
    int b = row >> 5, g = row & 31;
    const float* src = x + ((size_t)b * SEQ + (size_t)g * GSTR) * DIM;
    f4 v = *(const f4*)&src[t * 4];
    u16x4 o = { f2bf(v[0]), f2bf(v[1]), f2bf(v[2]), f2bf(v[3]) };
    *(u16x4*)&dst[t * 4] = o;
  } else {
    u16x4 z = { 0, 0, 0, 0 };
    *(u16x4*)&dst[t * 4] = z;
  }
}

// ---------------- bf16 MFMA GEMM: C[M,N] = A[M,K] @ Bt[N,K]^T + bias ----------------
// 128x128 tile, BK=32, 4 waves (2x2), 16x16x32 MFMA.
// A/B fragments use IDENTICAL contiguous-8 k-position loads -> k-pairing correct
// for any HW k-slot permutation. C/D mapping: col=lane&15, row=(lane>>4)*4+r (measured).
__global__ __launch_bounds__(256) void gemm_bf16(
    const unsigned short* __restrict__ A, const unsigned short* __restrict__ Bt,
    const float* __restrict__ bias,
    float* __restrict__ Cf, int ldcf,
    unsigned short* __restrict__ Cb, int ldcb,
    int M, int N, int K)
{
  __shared__ __align__(16) unsigned short As[128 * 32];
  __shared__ __align__(16) unsigned short Bs[128 * 32];
  const int tid = threadIdx.x;
  const int lane = tid & 63;
  const int w = tid >> 6;
  const int wr = w >> 1, wc = w & 1;
  const int tm = blockIdx.y << 7, tn = blockIdx.x << 7;
  const int r0 = tid >> 2;
  const int c0 = (tid & 3) << 3;   // element (bf16) offset within 32-wide k slab
  const unsigned short* Ag0 = A + (size_t)(tm + r0) * K + c0;
  const unsigned short* Ag1 = A + (size_t)(tm + r0 + 64) * K + c0;
  const unsigned short* Bg0 = Bt + (size_t)(tn + r0) * K + c0;
  const unsigned short* Bg1 = Bt + (size_t)(tn + r0 + 64) * K + c0;

  f32x4 zero4 = { 0.f, 0.f, 0.f, 0.f };
  f32x4 acc[4][4];
  #pragma unroll
  for (int m = 0; m < 4; ++m)
    #pragma unroll
    for (int n = 0; n < 4; ++n) acc[m][n] = zero4;

  i32x4 a0 = *(const i32x4*)(Ag0);
  i32x4 a1 = *(const i32x4*)(Ag1);
  i32x4 b0 = *(const i32x4*)(Bg0);
  i32x4 b1 = *(const i32x4*)(Bg1);

  const int fr = lane & 15, fg = lane >> 4;
  for (int kk = 0; kk < K; kk += 32){
    __syncthreads();
    *(i32x4*)&As[tid * 8]        = a0;
    *(i32x4*)&As[tid * 8 + 2048] = a1;
    *(i32x4*)&Bs[tid * 8]        = b0;
    *(i32x4*)&Bs[tid * 8 + 2048] = b1;
    __syncthreads();
    if (kk + 32 < K){
      a0 = *(const i32x4*)(Ag0 + kk + 32);
      a1 = *(const i32x4*)(Ag1 + kk + 32);
      b0 = *(const i32x4*)(Bg0 + kk + 32);
      b1 = *(const i32x4*)(Bg1 + kk + 32);
    }
    s16x8 af[4], bfv[4];
    #pragma unroll
    for (int m = 0; m < 4; ++m)
      af[m] = *(const s16x8*)&As[(wr * 64 + m * 16 + fr) * 32 + fg * 8];
    #pragma unroll
    for (int n = 0; n < 4; ++n)
      bfv[n] = *(const s16x8*)&Bs[(wc * 64 + n * 16 + fr) * 32 + fg * 8];
    #pragma unroll
    for (int m = 0; m < 4; ++m)
      #pragma unroll
      for (int n = 0; n < 4; ++n)
        acc[m][n] = __builtin_amdgcn_mfma_f32_16x16x32_bf16(af[m], bfv[n], acc[m][n], 0, 0, 0);
  }
  // epilogue
  #pragma unroll
  for (int m = 0; m < 4; ++m){
    #pragma unroll
    for (int n = 0; n < 4; ++n){
      int col = tn + wc * 64 + n * 16 + fr;
      float bv = bias ? bias[col] : 0.f;
      #pragma unroll
      for (int r = 0; r < 4; ++r){
        int row = tm + wr * 64 + m * 16 + fg * 4 + r;
        float v = acc[m][n][r] + bv;
        if (Cf) Cf[(size_t)row * ldcf + col] = v;
        if (Cb) Cb[(size_t)row * ldcb + col] = f2bf(v);
      }
    }
  }
}

// ---------------- local window attention ----------------
// grid 256: block = (b, w, h); 256 q rows, 256 keys, fp32.
__global__ __launch_bounds__(256) void local_attn(
    const float* __restrict__ lq, const float* __restrict__ lk,
    const float* __restrict__ lv, unsigned short* __restrict__ hcat)
{
  __shared__ __align__(16) float Kt[64 * 256];   // [d][j]
  __shared__ __align__(16) float Vs[256 * 64];   // [j][d]
  __shared__ __align__(16) float pT[4][256][4];  // per wave [key][q]
  __shared__ __align__(16) float qT[4][64][4];   // per wave [d][q]
  const int tid = threadIdx.x, lane = tid & 63, wv = tid >> 6;
  const int blk = blockIdx.x;
  const int h = blk & 15, w = (blk >> 4) & 7, b = blk >> 7;
  const size_t base = ((size_t)b * SEQ + (size_t)w * LWIN) * DIM + (size_t)h * DK;
  {
    const float* kr = lk + base + (size_t)tid * DIM;
    const float* vr = lv + base + (size_t)tid * DIM;
    #pragma unroll
    for (int i = 0; i < 16; ++i){
      int d0 = (((tid & 15) + i) & 15) << 2;   // rotated to spread banks
      f4 kv = *(const f4*)&kr[d0];
      Kt[(d0+0)*256 + tid] = kv[0]; Kt[(d0+1)*256 + tid] = kv[1];
      Kt[(d0+2)*256 + tid] = kv[2]; Kt[(d0+3)*256 + tid] = kv[3];
      f4 vv = *(const f4*)&vr[d0];
      *(f4*)&Vs[tid * 64 + d0] = vv;
    }
  }
  __syncthreads();
  for (int p = 0; p < 16; ++p){
    const int q0 = wv * 64 + p * 4;
    {
      f4 qv;
      #pragma unroll
      for (int i = 0; i < 4; ++i) qv[i] = lq[base + (size_t)(q0 + i) * DIM + lane];
      *(f4*)&qT[wv][lane][0] = qv;
    }
    float s[4][4];
    #pragma unroll
    for (int qi = 0; qi < 4; ++qi)
      #pragma unroll
      for (int ki = 0; ki < 4; ++ki) s[qi][ki] = 0.f;
    #pragma unroll 8
    for (int d = 0; d < 64; ++d){
      f4 k4 = *(const f4*)&Kt[d * 256 + (lane << 2)];
      f4 q4 = *(const f4*)&qT[wv][d][0];
      #pragma unroll
      for (int qi = 0; qi < 4; ++qi)
        #pragma unroll
        for (int ki = 0; ki < 4; ++ki)
          s[qi][ki] = fmaf(q4[qi], k4[ki], s[qi][ki]);
    }
    #pragma unroll
    for (int qi = 0; qi < 4; ++qi)
      #pragma unroll
      for (int ki = 0; ki < 4; ++ki) s[qi][ki] *= SCALE_F;
    float pr[4][4];
    #pragma unroll
    for (int qi = 0; qi < 4; ++qi){
      float mx = fmaxf(fmaxf(s[qi][0], s[qi][1]), fmaxf(s[qi][2], s[qi][3]));
      #pragma unroll
      for (int off = 1; off < 64; off <<= 1) mx = fmaxf(mx, __shfl_xor(mx, off));
      float es = 0.f;
      #pragma unroll
      for (int ki = 0; ki < 4; ++ki){ float e = __expf(s[qi][ki] - mx); pr[qi][ki] = e; es += e; }
      #pragma unroll
      for (int off = 1; off < 64; off <<= 1) es += __shfl_xor(es, off);
      float inv = 1.f / es;
      #pragma unroll
      for (int ki = 0; ki < 4; ++ki) pr[qi][ki] *= inv;
    }
    #pragma unroll
    for (int ki = 0; ki < 4; ++ki){
      f4 wv4 = { pr[0][ki], pr[1][ki], pr[2][ki], pr[3][ki] };
      *(f4*)&pT[wv][(lane << 2) + ki][0] = wv4;
    }
    float o0 = 0.f, o1 = 0.f, o2 = 0.f, o3 = 0.f;
    #pragma unroll 8
    for (int j = 0; j < 256; ++j){
      float v = Vs[j * 64 + lane];
      f4 p4 = *(const f4*)&pT[wv][j][0];
      o0 = fmaf(p4[0], v, o0); o1 = fmaf(p4[1], v, o1);
      o2 = fmaf(p4[2], v, o2); o3 = fmaf(p4[3], v, o3);
    }
    size_t tok = (size_t)b * SEQ + (size_t)w * LWIN + q0;
    hcat[(tok + 0) * 2048 + h * DK + lane] = f2bf(o0);
    hcat[(tok + 1) * 2048 + h * DK + lane] = f2bf(o1);
    hcat[(tok + 2) * 2048 + h * DK + lane] = f2bf(o2);
    hcat[(tok + 3) * 2048 + h * DK + lane] = f2bf(o3);
  }
}

// ---------------- global attention (32 keys) ----------------
// grid 256: block = (b, c, h); q rows c*256..+255, keys = 32 global tokens.
__global__ __launch_bounds__(256) void global_attn(
    const float* __restrict__ gq, const float* __restrict__ gkf,
    const float* __restrict__ gvf, unsigned short* __restrict__ hcat)
{
  __shared__ __align__(16) float Kt[64 * 32];    // [d][g]
  __shared__ __align__(16) float Vs[32 * 64];    // [g][d]
  __shared__ __align__(16) float pT[4][32][8];   // per wave [key][q]
  __shared__ __align__(16) float qT[4][64][8];   // per wave [d][q]
  const int tid = threadIdx.x, lane = tid & 63, wv = tid >> 6;
  const int blk = blockIdx.x;
  const int h = blk & 15, c = (blk >> 4) & 7, b = blk >> 7;
  {
    int g = tid >> 3;
    int d0 = (tid & 7) << 3;
    const float* kr = gkf + (size_t)(b * GCNT + g) * DIM + h * DK + d0;
    const float* vr = gvf + (size_t)(b * GCNT + g) * DIM + h * DK + d0;
    f4 k1 = *(const f4*)&kr[0]; f4 k2 = *(const f4*)&kr[4];
    #pragma unroll
    for (int i = 0; i < 4; ++i){ Kt[(d0+i)*32 + g] = k1[i]; Kt[(d0+4+i)*32 + g] = k2[i]; }
    *(f4*)&Vs[g * 64 + d0]     = *(const f4*)&vr[0];
    *(f4*)&Vs[g * 64 + d0 + 4] = *(const f4*)&vr[4];
  }
  __syncthreads();
  const size_t qbase = ((size_t)b * SEQ + (size_t)c * 256) * DIM + (size_t)h * DK;
  const int jg = lane & 31, qg = lane >> 5;
  for (int p = 0; p < 8; ++p){
    const int q0 = wv * 64 + p * 8;
    {
      float qv[8];
      #pragma unroll
      for (int i = 0; i < 8; ++i) qv[i] = gq[qbase + (size_t)(q0 + i) * DIM + lane];
      f4 qa = { qv[0], qv[1], qv[2], qv[3] };
      f4 qb = { qv[4], qv[5], qv[6], qv[7] };
      *(f4*)&qT[wv][lane][0] = qa;
      *(f4*)&qT[wv][lane][4] = qb;
    }
    float s[4];
    #pragma unroll
    for (int qi = 0; qi < 4; ++qi) s[qi] = 0.f;
    #pragma unroll 8
    for (int d = 0; d < 64; ++d){
      float k = Kt[d * 32 + jg];
      f4 q4 = *(const f4*)&qT[wv][d][qg * 4];
      #pragma unroll
      for (int qi = 0; qi < 4; ++qi) s[qi] = fmaf(q4[qi], k, s[qi]);
    }
    float e[4];
    #pragma unroll
    for (int qi = 0; qi < 4; ++qi){
      float sv = s[qi] * SCALE_F;
      float mx = sv;
      #pragma unroll
      for (int off = 1; off < 32; off <<= 1) mx = fmaxf(mx, __shfl_xor(mx, off));
      float ev = __expf(sv - mx);
      float es = ev;
      #pragma unroll
      for (int off = 1; off < 32; off <<= 1) es += __shfl_xor(es, off);
      e[qi] = ev / es;
    }
    f4 ew = { e[0], e[1], e[2], e[3] };
    *(f4*)&pT[wv][jg][qg * 4] = ew;
    float o[8];
    #pragma unroll
    for (int i = 0; i < 8; ++i) o[i] = 0.f;
    #pragma unroll
    for (int j = 0; j < 32; ++j){
      float v = Vs[j * 64 + lane];
      f4 pa = *(const f4*)&pT[wv][j][0];
      f4 pb = *(const f4*)&pT[wv][j][4];
      o[0] = fmaf(pa[0], v, o[0]); o[1] = fmaf(pa[1], v, o[1]);
      o[2] = fmaf(pa[2], v, o[2]); o[3] = fmaf(pa[3], v, o[3]);
      o[4] = fmaf(pb[0], v, o[4]); o[5] = fmaf(pb[1], v, o[5]);
      o[6] = fmaf(pb[2], v, o[6]); o[7] = fmaf(pb[3], v, o[7]);
    }
    size_t tok = (size_t)b * SEQ + (size_t)c * 256 + q0;
    #pragma unroll
    for (int i = 0; i < 8; ++i)
      hcat[(tok + i) * 2048 + 1024 + h * DK + lane] = f2bf(o[i]);
  }
}

// ---------------- sliding-window attention (flash over 3 tiles) ----------------
// grid 256: block = (b, c, h); q rows c*256..+255; key tiles {c-1,c,c+1}.
__global__ __launch_bounds__(256) void sliding_attn(
    const float* __restrict__ sq, const float* __restrict__ sk,
    const float* __restrict__ sv, unsigned short* __restrict__ out)
{
  __shared__ __align__(16) unsigned short KtB[64 * 256];  // [d][j] bf16
  __shared__ __align__(16) unsigned short VsB[256 * 64];  // [j][d] bf16
  __shared__ __align__(16) float O[256 * 64];             // [q][d] accumulator
  __shared__ __align__(16) float pT[4][256][4];
  __shared__ __align__(16) float qT[4][64][4];
  __shared__ float ml[256 * 2];                           // [q]{m,l}
  const int tid = threadIdx.x, lane = tid & 63, wv = tid >> 6;
  const int blk = blockIdx.x;
  const int h = blk & 15, c = (blk >> 4) & 7, b = blk >> 7;
  const size_t kvb = (size_t)b * SEQ * DIM + (size_t)h * DK;
  const size_t qb  = ((size_t)b * SEQ + (size_t)c * 256) * DIM + (size_t)h * DK;

  for (int i = tid; i < 256 * 64; i += 256) O[i] = 0.f;
  if (tid < 256){ ml[tid * 2] = NEG_INF; ml[tid * 2 + 1] = 0.f; }

  const int tlo = (c > 0) ? c - 1 : 0;
  const int thi = (c < 7) ? c + 1 : 7;
  for (int t = tlo; t <= thi; ++t){
    __syncthreads();
    {
      const float* kr = sk + kvb + (size_t)(t * 256 + tid) * DIM;
      const float* vr = sv + kvb + (size_t)(t * 256 + tid) * DIM;
      #pragma unroll
      for (int i = 0; i < 16; ++i){
        int d0 = (((tid & 15) + i) & 15) << 2;
        f4 kv = *(const f4*)&kr[d0];
        KtB[(d0+0)*256 + tid] = f2bf(kv[0]); KtB[(d0+1)*256 + tid] = f2bf(kv[1]);
        KtB[(d0+2)*256 + tid] = f2bf(kv[2]); KtB[(d0+3)*256 + tid] = f2bf(kv[3]);
        f4 vv = *(const f4*)&vr[d0];
        u16x4 vb = { f2bf(vv[0]), f2bf(vv[1]), f2bf(vv[2]), f2bf(vv[3]) };
        *(u16x4*)&VsB[tid * 64 + d0] = vb;
      }
    }
    __syncthreads();
    for (int p = 0; p < 16; ++p){
      const int q0 = wv * 64 + p * 4;   // local q within chunk
      {
        f4 qv;
        #pragma unroll
        for (int i = 0; i < 4; ++i) qv[i] = sq[qb + (size_t)(q0 + i) * DIM + lane];
        *(f4*)&qT[wv][lane][0] = qv;
      }
      float s[4][4];
      #pragma unroll
      for (int qi = 0; qi < 4; ++qi)
        #pragma unroll
        for (int ki = 0; ki < 4; ++ki) s[qi][ki] = 0.f;
      #pragma unroll 8
      for (int d = 0; d < 64; ++d){
        u16x4 k4 = *(const u16x4*)&KtB[d * 256 + (lane << 2)];
        f4 q4 = *(const f4*)&qT[wv][d][0];
        float kf0 = bf2f(k4[0]), kf1 = bf2f(k4[1]), kf2 = bf2f(k4[2]), kf3 = bf2f(k4[3]);
        #pragma unroll
        for (int qi = 0; qi < 4; ++qi){
          s[qi][0] = fmaf(q4[qi], kf0, s[qi][0]);
          s[qi][1] = fmaf(q4[qi], kf1, s[qi][1]);
          s[qi][2] = fmaf(q4[qi], kf2, s[qi][2]);
          s[qi][3] = fmaf(q4[qi], kf3, s[qi][3]);
        }
      }
      const int jb = t * 256 + (lane << 2);
      const int qglob = c * 256 + q0;
      float e[4][4], sc4[4];
      #pragma unroll
      for (int qi = 0; qi < 4; ++qi){
        #pragma unroll
        for (int ki = 0; ki < 4; ++ki){
          int dq = (qglob + qi) - (jb + ki);
          bool valid = (unsigned)(dq + SWHALF) <= (unsigned)(2 * SWHALF);
          s[qi][ki] = valid ? s[qi][ki] * SCALE_F : NEG_INF;
        }
        float mx = fmaxf(fmaxf(s[qi][0], s[qi][1]), fmaxf(s[qi][2], s[qi][3]));
        #pragma unroll
        for (int off = 1; off < 64; off <<= 1) mx = fmaxf(mx, __shfl_xor(mx, off));
        float mo = ml[(q0 + qi) * 2];
        float mn = fmaxf(mo, mx);
        float sc = __expf(mo - mn);
        float es = 0.f;
        #pragma unroll
        for (int ki = 0; ki < 4; ++ki){ float ev = __expf(s[qi][ki] - mn); e[qi][ki] = ev; es += ev; }
        #pragma unroll
        for (int off = 1; off < 64; off <<= 1) es += __shfl_xor(es, off);
        float lo = ml[(q0 + qi) * 2 + 1];
        ml[(q0 + qi) * 2]     = mn;
        ml[(q0 + qi) * 2 + 1] = lo * sc + es;
        sc4[qi] = sc;
      }
      #pragma unroll
      for (int ki = 0; ki < 4; ++ki){
        f4 wv4 = { e[0][ki], e[1][ki], e[2][ki], e[3][ki] };
        *(f4*)&pT[wv][(lane << 2) + ki][0] = wv4;
      }
      float o0 = O[(q0+0)*64 + lane] * sc4[0];
      float o1 = O[(q0+1)*64 + lane] * sc4[1];
      float o2 = O[(q0+2)*64 + lane] * sc4[2];
      float o3 = O[(q0+3)*64 + lane] * sc4[3];
      #pragma unroll 8
      for (int j = 0; j < 256; ++j){
        float v = bf2f(VsB[j * 64 + lane]);
        f4 p4 = *(const f4*)&pT[wv][j][0];
        o0 = fmaf(p4[0], v, o0); o1 = fmaf(p4[1], v, o1);
        o2 = fmaf(p4[2], v, o2); o3 = fmaf(p4[3], v, o3);
      }
      O[(q0+0)*64 + lane] = o0; O[(q0+1)*64 + lane] = o1;
      O[(q0+2)*64 + lane] = o2; O[(q0+3)*64 + lane] = o3;
    }
  }
  // epilogue: normalize + store bf16
  for (int p = 0; p < 16; ++p){
    int q0 = wv * 64 + p * 4;
    #pragma unroll
    for (int qi = 0; qi < 4; ++qi){
      int q = q0 + qi;
      float val = O[q * 64 + lane] / ml[q * 2 + 1];
      out[((size_t)b * SEQ + (size_t)c * 256 + q) * DIM + h * DK + lane] = f2bf(val);
    }
  }
}

// ---------------- fused residual + LayerNorm ----------------
// y = LN(x + dlt); writes fp32 (outf) and/or bf16 strided (outb).
__global__ __launch_bounds__(256) void ln_fused(
    const float* __restrict__ x, const float* __restrict__ dlt,
    const float* __restrict__ g, const float* __restrict__ bta,
    float* __restrict__ outf, unsigned short* __restrict__ outb, int ldo)
{
  const int row = blockIdx.x;
  const int t = threadIdx.x, lane = t & 63, wv = t >> 6;
  const float* xr = x + (size_t)row * DIM;
  const float* dr = dlt + (size_t)row * DIM;
  f4 xv = *(const f4*)&xr[t * 4];
  f4 dv = *(const f4*)&dr[t * 4];
  f4 y = xv + dv;
  float s = y[0] + y[1] + y[2] + y[3];
  float ss = y[0]*y[0] + y[1]*y[1] + y[2]*y[2] + y[3]*y[3];
  #pragma unroll
  for (int off = 1; off < 64; off <<= 1){ s += __shfl_xor(s, off); ss += __shfl_xor(ss, off); }
  __shared__ float red[8];
  if (lane == 0){ red[wv] = s; red[wv + 4] = ss; }
  __syncthreads();
  float S = red[0] + red[1] + red[2] + red[3];
  float SS = red[4] + red[5] + red[6] + red[7];
  float mu = S * (1.f / DIM);
  float var = SS * (1.f / DIM) - mu * mu;
  float rs = rsqrtf(var + 1e-5f);
  f4 gv = *(const f4*)&g[t * 4];
  f4 bv = *(const f4*)&bta[t * 4];
  f4 o;
  #pragma unroll
  for (int i = 0; i < 4; ++i) o[i] = (y[i] - mu) * rs * gv[i] + bv[i];
  if (outf) *(f4*)&outf[(size_t)row * ldo + t * 4] = o;
  if (outb){
    u16x4 ob = { f2bf(o[0]), f2bf(o[1]), f2bf(o[2]), f2bf(o[3]) };
    *(u16x4*)&outb[(size_t)row * ldo + t * 4] = ob;
  }
}

// ---------------- host launch ----------------
extern "C" void kernel_launch(void* const* d_in, const int* in_sizes, int n_in,
                              void* d_out, int out_size, void* d_ws, size_t ws_size,
                              hipStream_t stream){
  (void)in_sizes; (void)n_in; (void)out_size; (void)ws_size;
  const float* x      = (const float*)d_in[0];
  const float* lq_w   = (const float*)d_in[1];  const float* lq_b  = (const float*)d_in[2];
  const float* lk_w   = (const float*)d_in[3];  const float* lk_b  = (const float*)d_in[4];
  const float* lv_w   = (const float*)d_in[5];  const float* lv_b  = (const float*)d_in[6];
  const float* gq_w   = (const float*)d_in[7];  const float* gq_b  = (const float*)d_in[8];
  const float* gk_w   = (const float*)d_in[9];  const float* gk_b  = (const float*)d_in[10];
  const float* gv_w   = (const float*)d_in[11]; const float* gv_b  = (const float*)d_in[12];
  const float* ho_w   = (const float*)d_in[13]; const float* ho_b  = (const float*)d_in[14];
  const float* hln_g  = (const float*)d_in[15]; const float* hln_b = (const float*)d_in[16];
  const float* sq_w   = (const float*)d_in[17]; const float* sq_b  = (const float*)d_in[18];
  const float* sk_w   = (const float*)d_in[19]; const float* sk_b  = (const float*)d_in[20];
  const float* sv_w   = (const float*)d_in[21]; const float* sv_b  = (const float*)d_in[22];
  const float* so_w   = (const float*)d_in[23]; const float* so_b  = (const float*)d_in[24];
  const float* cb_w   = (const float*)d_in[25]; const float* cb_b  = (const float*)d_in[26];
  const float* ln_g   = (const float*)d_in[27]; const float* ln_b  = (const float*)d_in[28];

  const size_t M = (size_t)BATCH * SEQ;      // 4096
  char* ws = (char*)d_ws;
  size_t off = 0;
  auto alloc = [&](size_t bytes) -> void* {
    void* p = ws + off; off += (bytes + 255) & ~(size_t)255; return p;
  };
  unsigned short* xb    = (unsigned short*)alloc(M * DIM * 2);
  unsigned short* wt_lq = (unsigned short*)alloc((size_t)DIM * DIM * 2);
  unsigned short* wt_lk = (unsigned short*)alloc((size_t)DIM * DIM * 2);
  unsigned short* wt_lv = (unsigned short*)alloc((size_t)DIM * DIM * 2);
  unsigned short* wt_gq = (unsigned short*)alloc((size_t)DIM * DIM * 2);
  unsigned short* wt_gk = (unsigned short*)alloc((size_t)DIM * DIM * 2);
  unsigned short* wt_gv = (unsigned short*)alloc((size_t)DIM * DIM * 2);
  unsigned short* wt_sq = (unsigned short*)alloc((size_t)DIM * DIM * 2);
  unsigned short* wt_sk = (unsigned short*)alloc((size_t)DIM * DIM * 2);
  unsigned short* wt_sv = (unsigned short*)alloc((size_t)DIM * DIM * 2);
  unsigned short* wt_so = (unsigned short*)alloc((size_t)DIM * DIM * 2);
  unsigned short* wt_ho = (unsigned short*)alloc((size_t)DIM * 2 * DIM * 2);
  unsigned short* wt_cb = (unsigned short*)alloc((size_t)DIM * 2 * DIM * 2);
  unsigned short* gcb   = (unsigned short*)alloc((size_t)128 * DIM * 2);
  unsigned short* hcat  = (unsigned short*)alloc(M * 2 * DIM * 2);
  unsigned short* ccat  = (unsigned short*)alloc(M * 2 * DIM * 2);
  unsigned short* satt  = (unsigned short*)alloc(M * DIM * 2);
  float* A1  = (float*)alloc(M * DIM * 4);
  float* A2  = (float*)alloc(M * DIM * 4);
  float* A3  = (float*)alloc(M * DIM * 4);
  float* gkf = (float*)alloc((size_t)128 * DIM * 4);
  float* gvf = (float*)alloc((size_t)128 * DIM * 4);

  dim3 b256(256);
  // ---- casts / transposes ----
  cast_bf16_kernel<<<dim3((M * DIM) / 1024), b256, 0, stream>>>(x, xb, (int)(M * DIM));
  dim3 tg(DIM / 32, DIM / 32);
  transpose_cast<<<tg, b256, 0, stream>>>(lq_w, wt_lq, DIM, DIM);
  transpose_cast<<<tg, b256, 0, stream>>>(lk_w, wt_lk, DIM, DIM);
  transpose_cast<<<tg, b256, 0, stream>>>(lv_w, wt_lv, DIM, DIM);
  transpose_cast<<<tg, b256, 0, stream>>>(gq_w, wt_gq, DIM, DIM);
  transpose_cast<<<tg, b256, 0, stream>>>(gk_w, wt_gk, DIM, DIM);
  transpose_cast<<<tg, b256, 0, stream>>>(gv_w, wt_gv, DIM, DIM);
  transpose_cast<<<tg, b256, 0, stream>>>(sq_w, wt_sq, DIM, DIM);
  transpose_cast<<<tg, b256, 0, stream>>>(sk_w, wt_sk, DIM, DIM);
  transpose_cast<<<tg, b256, 0, stream>>>(sv_w, wt_sv, DIM, DIM);
  transpose_cast<<<tg, b256, 0, stream>>>(so_w, wt_so, DIM, DIM);
  dim3 tg2(DIM / 32, (2 * DIM) / 32);
  transpose_cast<<<tg2, b256, 0, stream>>>(ho_w, wt_ho, 2 * DIM, DIM);
  transpose_cast<<<tg2, b256, 0, stream>>>(cb_w, wt_cb, 2 * DIM, DIM);
  gc_extract<<<dim3(128), b256, 0, stream>>>(x, gcb);

  dim3 gemm_grid(DIM / 128, (int)(M / 128));       // (8, 32)
  dim3 gemm_grid_small(DIM / 128, 1);              // (8, 1)

  // ---- sliding branch first (frees A buffers) ----
  gemm_bf16<<<gemm_grid, b256, 0, stream>>>(xb, wt_sq, sq_b, A1, DIM, nullptr, 0, (int)M, DIM, DIM);
  gemm_bf16<<<gemm_grid, b256, 0, stream>>>(xb, wt_sk, sk_b, A2, DIM, nullptr, 0, (int)M, DIM, DIM);
  gemm_bf16<<<gemm_grid, b256, 0, stream>>>(xb, wt_sv, sv_b, A3, DIM, nullptr, 0, (int)M, DIM, DIM);
  sliding_attn<<<dim3(256), b256, 0, stream>>>(A1, A2, A3, satt);
  gemm_bf16<<<gemm_grid, b256, 0, stream>>>(satt, wt_so, so_b, nullptr, 0, ccat + 1024, 2 * DIM, (int)M, DIM, DIM);

  // ---- local branch ----
  gemm_bf16<<<gemm_grid, b256, 0, stream>>>(xb, wt_lq, lq_b, A1, DIM, nullptr, 0, (int)M, DIM, DIM);
  gemm_bf16<<<gemm_grid, b256, 0, stream>>>(xb, wt_lk, lk_b, A2, DIM, nullptr, 0, (int)M, DIM, DIM);
  gemm_bf16<<<gemm_grid, b256, 0, stream>>>(xb, wt_lv, lv_b, A3, DIM, nullptr, 0, (int)M, DIM, DIM);
  local_attn<<<dim3(256), b256, 0, stream>>>(A1, A2, A3, hcat);

  // ---- global branch ----
  gemm_bf16<<<gemm_grid, b256, 0, stream>>>(xb, wt_gq, gq_b, A1, DIM, nullptr, 0, (int)M, DIM, DIM);
  gemm_bf16<<<gemm_grid_small, b256, 0, stream>>>(gcb, wt_gk, gk_b, gkf, DIM, nullptr, 0, 128, DIM, DIM);
  gemm_bf16<<<gemm_grid_small, b256, 0, stream>>>(gcb, wt_gv, gv_b, gvf, DIM, nullptr, 0, 128, DIM, DIM);
  global_attn<<<dim3(256), b256, 0, stream>>>(A1, gkf, gvf, hcat);

  // ---- h_out projection + LN1 ----
  gemm_bf16<<<gemm_grid, b256, 0, stream>>>(hcat, wt_ho, ho_b, A2, DIM, nullptr, 0, (int)M, DIM, 2 * DIM);
  ln_fused<<<dim3((int)M), b256, 0, stream>>>(x, A2, hln_g, hln_b, nullptr, ccat, 2 * DIM);

  // ---- combine + LN2 ----
  gemm_bf16<<<gemm_grid, b256, 0, stream>>>(ccat, wt_cb, cb_b, A1, DIM, nullptr, 0, (int)M, DIM, 2 * DIM);
  ln_fused<<<dim3((int)M), b256, 0, stream>>>(x, A1, ln_g, ln_b, (float*)d_out, nullptr, DIM);
}

// Round 3
// 680.943 us; speedup vs baseline: 1.6639x; 1.6639x over previous
//
#include <hip/hip_runtime.h>

// ---------------- problem constants ----------------
#define BATCH 2
#define SEQ   2048
#define DIM   1024
#define NH    16
#define DK    64
#define SCALE_F 0.125f
#define MASKED  -2e30f
#define MINIT   -1e30f

typedef __attribute__((ext_vector_type(4))) float f4;
typedef __attribute__((ext_vector_type(4))) float f32x4;
typedef __attribute__((ext_vector_type(8))) short s16x8;
typedef __attribute__((ext_vector_type(4))) int  i32x4;
typedef __attribute__((ext_vector_type(4))) unsigned short u16x4;

__device__ __forceinline__ float bf2f(unsigned short u){ return __uint_as_float(((unsigned)u) << 16); }
__device__ __forceinline__ unsigned short f2bf(float f){
  unsigned u = __float_as_uint(f);
  u += 0x7FFFu + ((u >> 16) & 1u);
  return (unsigned short)(u >> 16);
}

// async global->LDS, 16B per lane. LDS dest = wave-uniform base + lane*16.
#define ASYNC_LDS16(g, l) \
  __builtin_amdgcn_global_load_lds((const __attribute__((address_space(1))) void*)(g), \
                                   (__attribute__((address_space(3))) void*)(l), 16, 0, 0)

// ---------------- cast fp32 -> bf16 (vectorized) ----------------
__global__ __launch_bounds__(256) void cast_bf16_kernel(const float* __restrict__ in,
                                                        unsigned short* __restrict__ out, int n){
  int i = (blockIdx.x * 256 + threadIdx.x) * 4;
  if (i < n){
    f4 v = *(const f4*)&in[i];
    u16x4 o = { f2bf(v[0]), f2bf(v[1]), f2bf(v[2]), f2bf(v[3]) };
    *(u16x4*)&out[i] = o;
  }
}

// ---------------- batched transpose + cast: W (K x DIM fp32) -> Wt (DIM x K bf16) ----------------
struct TCP { const float* w[12]; unsigned short* wt[12]; };
__global__ __launch_bounds__(256) void transpose_cast_b(TCP P, int K){
  const float* W = P.w[blockIdx.z];
  unsigned short* Wt = P.wt[blockIdx.z];
  __shared__ float tile[32][33];
  int x = threadIdx.x & 31, y = threadIdx.x >> 5;
  int bc = blockIdx.x << 5;   // over N (=DIM)
  int br = blockIdx.y << 5;   // over K
  #pragma unroll
  for (int yy = y; yy < 32; yy += 8)
    tile[yy][x] = W[(size_t)(br + yy) * DIM + bc + x];
  __syncthreads();
  #pragma unroll
  for (int yy = y; yy < 32; yy += 8)
    Wt[(size_t)(bc + yy) * K + br + x] = f2bf(tile[x][yy]);
}

// ---------------- gc extraction: x[:, ::64] -> bf16, padded to 128 rows ----------------
__global__ __launch_bounds__(256) void gc_extract(const float* __restrict__ x,
                                                  unsigned short* __restrict__ gcb){
  int row = blockIdx.x;         // 0..127
  int t = threadIdx.x;
  unsigned short* dst = gcb + (size_t)row * DIM;
  if (row < BATCH * 32){
    int b = row >> 5, g = row & 31;
    const float* src = x + ((size_t)b * SEQ + (size_t)g * 64) * DIM;
    f4 v = *(const f4*)&src[t * 4];
    u16x4 o = { f2bf(v[0]), f2bf(v[1]), f2bf(v[2]), f2bf(v[3]) };
    *(u16x4*)&dst[t * 4] = o;
  } else {
    u16x4 z = { 0, 0, 0, 0 };
    *(u16x4*)&dst[t * 4] = z;
  }
}

// ---------------- bf16 MFMA GEMM ----------------
// C[M,N] = A[M,K] @ Bt[N,K]^T + bias. 128x128 tile, BK=32, 4 waves, 16x16x32 MFMA.
// TRANSC=1: write C^T (operand-swap trick; epilogue stays coalesced) -> Ct[N-dim][M-dim].
// Staging: global_load_lds width 16 (LDS layout is linear in lane order).
template<int TRANSC>
__global__ __launch_bounds__(256) void gemm_bf16(
    const unsigned short* __restrict__ A, const unsigned short* __restrict__ Bt,
    const float* __restrict__ bias,
    float* __restrict__ Cf, int ldcf,
    unsigned short* __restrict__ Cb, int ldcb,
    int M, int N, int K)
{
  __shared__ __align__(16) unsigned short As[128 * 32];
  __shared__ __align__(16) unsigned short Bs[128 * 32];
  const int tid = threadIdx.x;
  const int lane = tid & 63;
  const int w = tid >> 6;
  const int wr = w >> 1, wc = w & 1;
  const int tm = blockIdx.y << 7, tn = blockIdx.x << 7;
  const int r0 = tid >> 2;
  const int c0 = (tid & 3) << 3;
  const unsigned short* Ag0 = A + (size_t)(tm + r0) * K + c0;
  const unsigned short* Ag1 = A + (size_t)(tm + r0 + 64) * K + c0;
  const unsigned short* Bg0 = Bt + (size_t)(tn + r0) * K + c0;
  const unsigned short* Bg1 = Bt + (size_t)(tn + r0 + 64) * K + c0;
  unsigned short* AsW0 = &As[w * 512];
  unsigned short* AsW1 = &As[w * 512 + 2048];
  unsigned short* BsW0 = &Bs[w * 512];
  unsigned short* BsW1 = &Bs[w * 512 + 2048];

  f32x4 acc[4][4];
  #pragma unroll
  for (int m = 0; m < 4; ++m)
    #pragma unroll
    for (int n = 0; n < 4; ++n) acc[m][n] = (f32x4){0.f, 0.f, 0.f, 0.f};

  const int fr = lane & 15, fg = lane >> 4;
  for (int kk = 0; kk < K; kk += 32){
    ASYNC_LDS16(Ag0 + kk, AsW0);
    ASYNC_LDS16(Ag1 + kk, AsW1);
    ASYNC_LDS16(Bg0 + kk, BsW0);
    ASYNC_LDS16(Bg1 + kk, BsW1);
    __syncthreads();
    s16x8 af[4], bfv[4];
    #pragma unroll
    for (int m = 0; m < 4; ++m)
      af[m] = *(const s16x8*)&As[(wr * 64 + m * 16 + fr) * 32 + fg * 8];
    #pragma unroll
    for (int n = 0; n < 4; ++n)
      bfv[n] = *(const s16x8*)&Bs[(wc * 64 + n * 16 + fr) * 32 + fg * 8];
    #pragma unroll
    for (int m = 0; m < 4; ++m)
      #pragma unroll
      for (int n = 0; n < 4; ++n){
        if (TRANSC)
          acc[m][n] = __builtin_amdgcn_mfma_f32_16x16x32_bf16(bfv[n], af[m], acc[m][n], 0, 0, 0);
        else
          acc[m][n] = __builtin_amdgcn_mfma_f32_16x16x32_bf16(af[m], bfv[n], acc[m][n], 0, 0, 0);
      }
    __syncthreads();
  }
  // epilogue
  #pragma unroll
  for (int m = 0; m < 4; ++m){
    #pragma unroll
    for (int n = 0; n < 4; ++n){
      if (!TRANSC){
        int col = tn + wc * 64 + n * 16 + fr;
        float bv = bias ? bias[col] : 0.f;
        #pragma unroll
        for (int r = 0; r < 4; ++r){
          int row = tm + wr * 64 + m * 16 + fg * 4 + r;
          float v = acc[m][n][r] + bv;
          if (Cf) Cf[(size_t)row * ldcf + col] = v;
          if (Cb) Cb[(size_t)row * ldcb + col] = f2bf(v);
        }
      } else {
        int colT = tm + wr * 64 + m * 16 + fr;           // token
        #pragma unroll
        for (int r = 0; r < 4; ++r){
          int rowT = tn + wc * 64 + n * 16 + fg * 4 + r; // d_out
          float v = acc[m][n][r] + (bias ? bias[rowT] : 0.f);
          Cb[(size_t)rowT * ldcb + colT] = f2bf(v);
        }
      }
    }
  }
}

// ---------------- unified MFMA flash attention ----------------
// MODE 0 = local window (256, block-diagonal), 1 = sliding band (|q-j|<=256), 2 = global (32 keys).
// Block = (b, qc, h): 64 q rows. 4 waves x 16 q. K/V tiles of 64 keys.
// Q,K bf16 token-major [tok][1024]; Vt bf16 transposed [1024][ldvt].
template<int MODE>
__global__ __launch_bounds__(256) void mfma_attn(
    const unsigned short* __restrict__ Qb,
    const unsigned short* __restrict__ Kb,
    const unsigned short* __restrict__ Vtb, int ldvt,
    unsigned short* __restrict__ Out, int ldo, int ocol)
{
  __shared__ __align__(16) unsigned short Ks[64][72];
  __shared__ __align__(16) unsigned short Vs[64][72];     // XOR-swizzled within rows
  __shared__ __align__(16) unsigned short Pl[4][16][72];  // per-wave P buffer
  const int tid = threadIdx.x, lane = tid & 63, wv = tid >> 6;
  const int fr = lane & 15, fg = lane >> 4;
  const int blk = blockIdx.x;              // b*512 + qc*16 + h
  const int h  = blk & 15;
  const int qc = (blk >> 4) & 31;
  const int b  = blk >> 9;
  const int q0 = qc * 64;                  // seq-local
  const int tq0 = b * SEQ + q0;            // token index
  int jlo, ntile;
  if (MODE == 0){ jlo = (qc >> 2) << 8; ntile = 4; }
  else if (MODE == 1){
    jlo = q0 - 256 < 0 ? 0 : q0 - 256;
    int jhi = q0 + 320 > SEQ ? SEQ : q0 + 320;
    ntile = (jhi - jlo) >> 6;
  } else { jlo = 0; ntile = 1; }
  const int ktok0 = (MODE == 2) ? b * 32 : b * SEQ;

  // Q fragments (held in registers for the whole block)
  s16x8 qf[2];
  {
    const size_t qrow = (size_t)(tq0 + wv * 16 + fr) * DIM + h * DK;
    qf[0] = *(const s16x8*)&Qb[qrow + fg * 8];
    qf[1] = *(const s16x8*)&Qb[qrow + 32 + fg * 8];
  }
  f32x4 of[4];
  #pragma unroll
  for (int dt = 0; dt < 4; ++dt) of[dt] = (f32x4){0.f, 0.f, 0.f, 0.f};
  f32x4 m4 = (f32x4){MINIT, MINIT, MINIT, MINIT};
  f32x4 l4 = (f32x4){0.f, 0.f, 0.f, 0.f};

  for (int t = 0; t < ntile; ++t){
    const int jb = jlo + t * 64;
    __syncthreads();
    // stage K [j][d] and Vt [d][j] (swizzled), 2 passes x 256 thr x 16B each
    #pragma unroll
    for (int p = 0; p < 2; ++p){
      int idx = p * 256 + tid;
      int row = idx >> 3, c8 = idx & 7;
      *(i32x4*)&Ks[row][c8 * 8] =
          *(const i32x4*)&Kb[(size_t)(ktok0 + jb + row) * DIM + h * DK + c8 * 8];
      i32x4 v = *(const i32x4*)&Vtb[(size_t)(h * DK + row) * ldvt + ktok0 + jb + c8 * 8];
      *(i32x4*)((char*)Vs + row * 144 + ((c8 * 16) ^ ((row & 7) << 4))) = v;
    }
    __syncthreads();
    // S = Q K^T  (lane holds: q = fg*4+r, j = t16*16+fr)
    f32x4 sf[4];
    #pragma unroll
    for (int t16 = 0; t16 < 4; ++t16){
      sf[t16] = (f32x4){0.f, 0.f, 0.f, 0.f};
      #pragma unroll
      for (int ks = 0; ks < 2; ++ks){
        s16x8 kf = *(const s16x8*)&Ks[t16 * 16 + fr][ks * 32 + fg * 8];
        sf[t16] = __builtin_amdgcn_mfma_f32_16x16x32_bf16(qf[ks], kf, sf[t16], 0, 0, 0);
      }
    }
    // mask + scale
    #pragma unroll
    for (int t16 = 0; t16 < 4; ++t16){
      int j = jb + t16 * 16 + fr;
      #pragma unroll
      for (int r = 0; r < 4; ++r){
        float v = sf[t16][r] * SCALE_F;
        bool valid = true;
        if (MODE == 1){ int dq = (q0 + wv * 16 + fg * 4 + r) - j; valid = (dq <= 256) && (dq >= -256); }
        if (MODE == 2){ valid = j < 32; }
        sf[t16][r] = valid ? v : MASKED;
      }
    }
    // row max over j (in-reg + 16-lane shfl butterfly)
    f32x4 mx;
    #pragma unroll
    for (int r = 0; r < 4; ++r)
      mx[r] = fmaxf(fmaxf(sf[0][r], sf[1][r]), fmaxf(sf[2][r], sf[3][r]));
    #pragma unroll
    for (int off = 1; off < 16; off <<= 1){
      #pragma unroll
      for (int r = 0; r < 4; ++r) mx[r] = fmaxf(mx[r], __shfl_xor(mx[r], off));
    }
    f32x4 sc;
    #pragma unroll
    for (int r = 0; r < 4; ++r){
      float mn = fmaxf(m4[r], mx[r]);
      sc[r] = __expf(m4[r] - mn);
      m4[r] = mn;
    }
    // exp, partial sums, P -> LDS (bf16)
    f32x4 sm = (f32x4){0.f, 0.f, 0.f, 0.f};
    #pragma unroll
    for (int t16 = 0; t16 < 4; ++t16){
      #pragma unroll
      for (int r = 0; r < 4; ++r){
        float e = __expf(sf[t16][r] - m4[r]);
        sm[r] += e;
        Pl[wv][fg * 4 + r][t16 * 16 + fr] = f2bf(e);
      }
    }
    #pragma unroll
    for (int off = 1; off < 16; off <<= 1){
      #pragma unroll
      for (int r = 0; r < 4; ++r) sm[r] += __shfl_xor(sm[r], off);
    }
    #pragma unroll
    for (int r = 0; r < 4; ++r) l4[r] = l4[r] * sc[r] + sm[r];
    // rescale O
    #pragma unroll
    for (int dt = 0; dt < 4; ++dt)
      #pragma unroll
      for (int r = 0; r < 4; ++r) of[dt][r] *= sc[r];
    // O += P V   (A = P rows, B = Vt rows; identical k(j)-slab mapping)
    #pragma unroll
    for (int ks2 = 0; ks2 < 2; ++ks2){
      s16x8 pa = *(const s16x8*)&Pl[wv][fr][ks2 * 32 + fg * 8];
      #pragma unroll
      for (int dt = 0; dt < 4; ++dt){
        int d = dt * 16 + fr;
        s16x8 vf = *(const s16x8*)((char*)Vs + d * 144 + ((ks2 * 64 + fg * 16) ^ ((d & 7) << 4)));
        of[dt] = __builtin_amdgcn_mfma_f32_16x16x32_bf16(pa, vf, of[dt], 0, 0, 0);
      }
    }
  }
  // epilogue: normalize + store
  #pragma unroll
  for (int dt = 0; dt < 4; ++dt){
    #pragma unroll
    for (int r = 0; r < 4; ++r){
      float val = of[dt][r] / l4[r];
      int q = tq0 + wv * 16 + fg * 4 + r;
      Out[(size_t)q * ldo + ocol + h * DK + dt * 16 + fr] = f2bf(val);
    }
  }
}

// ---------------- fused residual + LayerNorm ----------------
__global__ __launch_bounds__(256) void ln_fused(
    const float* __restrict__ x, const float* __restrict__ dlt,
    const float* __restrict__ g, const float* __restrict__ bta,
    float* __restrict__ outf, unsigned short* __restrict__ outb, int ldo)
{
  const int row = blockIdx.x;
  const int t = threadIdx.x, lane = t & 63, wv = t >> 6;
  const float* xr = x + (size_t)row * DIM;
  const float* dr = dlt + (size_t)row * DIM;
  f4 xv = *(const f4*)&xr[t * 4];
  f4 dv = *(const f4*)&dr[t * 4];
  f4 y = xv + dv;
  float s = y[0] + y[1] + y[2] + y[3];
  float ss = y[0]*y[0] + y[1]*y[1] + y[2]*y[2] + y[3]*y[3];
  #pragma unroll
  for (int off = 1; off < 64; off <<= 1){ s += __shfl_xor(s, off); ss += __shfl_xor(ss, off); }
  __shared__ float red[8];
  if (lane == 0){ red[wv] = s; red[wv + 4] = ss; }
  __syncthreads();
  float S = red[0] + red[1] + red[2] + red[3];
  float SS = red[4] + red[5] + red[6] + red[7];
  float mu = S * (1.f / DIM);
  float var = SS * (1.f / DIM) - mu * mu;
  float rs = rsqrtf(var + 1e-5f);
  f4 gv = *(const f4*)&g[t * 4];
  f4 bv = *(const f4*)&bta[t * 4];
  f4 o;
  #pragma unroll
  for (int i = 0; i < 4; ++i) o[i] = (y[i] - mu) * rs * gv[i] + bv[i];
  if (outf) *(f4*)&outf[(size_t)row * ldo + t * 4] = o;
  if (outb){
    u16x4 ob = { f2bf(o[0]), f2bf(o[1]), f2bf(o[2]), f2bf(o[3]) };
    *(u16x4*)&outb[(size_t)row * ldo + t * 4] = ob;
  }
}

// ---------------- host launch ----------------
extern "C" void kernel_launch(void* const* d_in, const int* in_sizes, int n_in,
                              void* d_out, int out_size, void* d_ws, size_t ws_size,
                              hipStream_t stream){
  (void)in_sizes; (void)n_in; (void)out_size; (void)ws_size;
  const float* x      = (const float*)d_in[0];
  const float* lq_w   = (const float*)d_in[1];  const float* lq_b  = (const float*)d_in[2];
  const float* lk_w   = (const float*)d_in[3];  const float* lk_b  = (const float*)d_in[4];
  const float* lv_w   = (const float*)d_in[5];  const float* lv_b  = (const float*)d_in[6];
  const float* gq_w   = (const float*)d_in[7];  const float* gq_b  = (const float*)d_in[8];
  const float* gk_w   = (const float*)d_in[9];  const float* gk_b  = (const float*)d_in[10];
  const float* gv_w   = (const float*)d_in[11]; const float* gv_b  = (const float*)d_in[12];
  const float* ho_w   = (const float*)d_in[13]; const float* ho_b  = (const float*)d_in[14];
  const float* hln_g  = (const float*)d_in[15]; const float* hln_b = (const float*)d_in[16];
  const float* sq_w   = (const float*)d_in[17]; const float* sq_b  = (const float*)d_in[18];
  const float* sk_w   = (const float*)d_in[19]; const float* sk_b  = (const float*)d_in[20];
  const float* sv_w   = (const float*)d_in[21]; const float* sv_b  = (const float*)d_in[22];
  const float* so_w   = (const float*)d_in[23]; const float* so_b  = (const float*)d_in[24];
  const float* cb_w   = (const float*)d_in[25]; const float* cb_b  = (const float*)d_in[26];
  const float* ln_g   = (const float*)d_in[27]; const float* ln_b  = (const float*)d_in[28];

  const size_t M = (size_t)BATCH * SEQ;      // 4096
  char* ws = (char*)d_ws;
  size_t off = 0;
  auto alloc = [&](size_t bytes) -> void* {
    void* p = ws + off; off += (bytes + 255) & ~(size_t)255; return p;
  };
  unsigned short* xb    = (unsigned short*)alloc(M * DIM * 2);
  unsigned short* wt_lq = (unsigned short*)alloc((size_t)DIM * DIM * 2);
  unsigned short* wt_lk = (unsigned short*)alloc((size_t)DIM * DIM * 2);
  unsigned short* wt_lv = (unsigned short*)alloc((size_t)DIM * DIM * 2);
  unsigned short* wt_gq = (unsigned short*)alloc((size_t)DIM * DIM * 2);
  unsigned short* wt_gk = (unsigned short*)alloc((size_t)DIM * DIM * 2);
  unsigned short* wt_gv = (unsigned short*)alloc((size_t)DIM * DIM * 2);
  unsigned short* wt_sq = (unsigned short*)alloc((size_t)DIM * DIM * 2);
  unsigned short* wt_sk = (unsigned short*)alloc((size_t)DIM * DIM * 2);
  unsigned short* wt_sv = (unsigned short*)alloc((size_t)DIM * DIM * 2);
  unsigned short* wt_so = (unsigned short*)alloc((size_t)DIM * DIM * 2);
  unsigned short* wt_ho = (unsigned short*)alloc((size_t)DIM * 2 * DIM * 2);
  unsigned short* wt_cb = (unsigned short*)alloc((size_t)DIM * 2 * DIM * 2);
  unsigned short* gcb   = (unsigned short*)alloc((size_t)128 * DIM * 2);
  unsigned short* qb    = (unsigned short*)alloc(M * DIM * 2);
  unsigned short* kb    = (unsigned short*)alloc(M * DIM * 2);
  unsigned short* vtb   = (unsigned short*)alloc(M * DIM * 2);   // [1024][4096] transposed
  unsigned short* gkb   = (unsigned short*)alloc((size_t)128 * DIM * 2);
  unsigned short* vtg   = (unsigned short*)alloc((size_t)128 * DIM * 2); // [1024][128]
  unsigned short* satt  = (unsigned short*)alloc(M * DIM * 2);
  unsigned short* hcat  = (unsigned short*)alloc(M * 2 * DIM * 2);
  unsigned short* ccat  = (unsigned short*)alloc(M * 2 * DIM * 2);
  float* Af             = (float*)alloc(M * DIM * 4);

  dim3 b256(256);
  // ---- casts / transposes ----
  cast_bf16_kernel<<<dim3((M * DIM) / 1024), b256, 0, stream>>>(x, xb, (int)(M * DIM));
  {
    TCP p1 = {};
    const float* ws_[10] = {lq_w, lk_w, lv_w, gq_w, gk_w, gv_w, sq_w, sk_w, sv_w, so_w};
    unsigned short* wts_[10] = {wt_lq, wt_lk, wt_lv, wt_gq, wt_gk, wt_gv, wt_sq, wt_sk, wt_sv, wt_so};
    for (int i = 0; i < 10; ++i){ p1.w[i] = ws_[i]; p1.wt[i] = wts_[i]; }
    transpose_cast_b<<<dim3(32, 32, 10), b256, 0, stream>>>(p1, DIM);
    TCP p2 = {};
    p2.w[0] = ho_w; p2.wt[0] = wt_ho;
    p2.w[1] = cb_w; p2.wt[1] = wt_cb;
    transpose_cast_b<<<dim3(32, 64, 2), b256, 0, stream>>>(p2, 2 * DIM);
  }
  gc_extract<<<dim3(128), b256, 0, stream>>>(x, gcb);

  dim3 gemm_grid(DIM / 128, (int)(M / 128));       // (8, 32)
  dim3 gemm_grid_small(DIM / 128, 1);              // (8, 1)
  dim3 attn_grid(1024);

  // ---- sliding branch ----
  gemm_bf16<0><<<gemm_grid, b256, 0, stream>>>(xb, wt_sq, sq_b, nullptr, 0, qb,  DIM, (int)M, DIM, DIM);
  gemm_bf16<0><<<gemm_grid, b256, 0, stream>>>(xb, wt_sk, sk_b, nullptr, 0, kb,  DIM, (int)M, DIM, DIM);
  gemm_bf16<1><<<gemm_grid, b256, 0, stream>>>(xb, wt_sv, sv_b, nullptr, 0, vtb, (int)M, (int)M, DIM, DIM);
  mfma_attn<1><<<attn_grid, b256, 0, stream>>>(qb, kb, vtb, (int)M, satt, DIM, 0);
  gemm_bf16<0><<<gemm_grid, b256, 0, stream>>>(satt, wt_so, so_b, nullptr, 0, ccat + 1024, 2 * DIM, (int)M, DIM, DIM);

  // ---- local branch ----
  gemm_bf16<0><<<gemm_grid, b256, 0, stream>>>(xb, wt_lq, lq_b, nullptr, 0, qb,  DIM, (int)M, DIM, DIM);
  gemm_bf16<0><<<gemm_grid, b256, 0, stream>>>(xb, wt_lk, lk_b, nullptr, 0, kb,  DIM, (int)M, DIM, DIM);
  gemm_bf16<1><<<gemm_grid, b256, 0, stream>>>(xb, wt_lv, lv_b, nullptr, 0, vtb, (int)M, (int)M, DIM, DIM);
  mfma_attn<0><<<attn_grid, b256, 0, stream>>>(qb, kb, vtb, (int)M, hcat, 2 * DIM, 0);

  // ---- global branch ----
  gemm_bf16<0><<<gemm_grid, b256, 0, stream>>>(xb, wt_gq, gq_b, nullptr, 0, qb, DIM, (int)M, DIM, DIM);
  gemm_bf16<0><<<gemm_grid_small, b256, 0, stream>>>(gcb, wt_gk, gk_b, nullptr, 0, gkb, DIM, 128, DIM, DIM);
  gemm_bf16<1><<<gemm_grid_small, b256, 0, stream>>>(gcb, wt_gv, gv_b, nullptr, 0, vtg, 128, 128, DIM, DIM);
  mfma_attn<2><<<attn_grid, b256, 0, stream>>>(qb, gkb, vtg, 128, hcat, 2 * DIM, 1024);

  // ---- h_out projection + LN1 ----
  gemm_bf16<0><<<gemm_grid, b256, 0, stream>>>(hcat, wt_ho, ho_b, Af, DIM, nullptr, 0, (int)M, DIM, 2 * DIM);
  ln_fused<<<dim3((int)M), b256, 0, stream>>>(x, Af, hln_g, hln_b, nullptr, ccat, 2 * DIM);

  // ---- combine + LN2 ----
  gemm_bf16<0><<<gemm_grid, b256, 0, stream>>>(ccat, wt_cb, cb_b, Af, DIM, nullptr, 0, (int)M, DIM, 2 * DIM);
  ln_fused<<<dim3((int)M), b256, 0, stream>>>(x, Af, ln_g, ln_b, (float*)d_out, nullptr, DIM);
}

// Round 4
// 565.190 us; speedup vs baseline: 2.0046x; 1.2048x over previous
//
#include <hip/hip_runtime.h>

// ---------------- problem constants ----------------
#define BATCH 2
#define SEQ   2048
#define DIM   1024
#define NH    16
#define DK    64
#define SCALE_F 0.125f
#define MASKED  -2e30f
#define MINIT   -1e30f

typedef __attribute__((ext_vector_type(4))) float f4;
typedef __attribute__((ext_vector_type(4))) float f32x4;
typedef __attribute__((ext_vector_type(8))) short s16x8;
typedef __attribute__((ext_vector_type(4))) int  i32x4;
typedef __attribute__((ext_vector_type(4))) unsigned short u16x4;

__device__ __forceinline__ float bf2f(unsigned short u){ return __uint_as_float(((unsigned)u) << 16); }
__device__ __forceinline__ unsigned short f2bf(float f){
  unsigned u = __float_as_uint(f);
  u += 0x7FFFu + ((u >> 16) & 1u);
  return (unsigned short)(u >> 16);
}

// async global->LDS, 16B per lane. LDS dest = wave-uniform base + lane*16.
#define ASYNC_LDS16(g, l) \
  __builtin_amdgcn_global_load_lds((const __attribute__((address_space(1))) void*)(g), \
                                   (__attribute__((address_space(3))) void*)(l), 16, 0, 0)

// ---------------- cast fp32 -> bf16 (vectorized) ----------------
__global__ __launch_bounds__(256) void cast_bf16_kernel(const float* __restrict__ in,
                                                        unsigned short* __restrict__ out, int n){
  int i = (blockIdx.x * 256 + threadIdx.x) * 4;
  if (i < n){
    f4 v = *(const f4*)&in[i];
    u16x4 o = { f2bf(v[0]), f2bf(v[1]), f2bf(v[2]), f2bf(v[3]) };
    *(u16x4*)&out[i] = o;
  }
}

// ---------------- batched transpose + cast: W (K x DIM fp32) -> Wt (DIM x K bf16) ----------------
struct TCP { const float* w[12]; unsigned short* wt[12]; };
__global__ __launch_bounds__(256) void transpose_cast_b(TCP P, int K){
  const float* W = P.w[blockIdx.z];
  unsigned short* Wt = P.wt[blockIdx.z];
  __shared__ float tile[32][33];
  int x = threadIdx.x & 31, y = threadIdx.x >> 5;
  int bc = blockIdx.x << 5;   // over N (=DIM)
  int br = blockIdx.y << 5;   // over K
  #pragma unroll
  for (int yy = y; yy < 32; yy += 8)
    tile[yy][x] = W[(size_t)(br + yy) * DIM + bc + x];
  __syncthreads();
  #pragma unroll
  for (int yy = y; yy < 32; yy += 8)
    Wt[(size_t)(bc + yy) * K + br + x] = f2bf(tile[x][yy]);
}

// ---------------- gc extraction: x[:, ::64] -> bf16, padded to 128 rows ----------------
__global__ __launch_bounds__(256) void gc_extract(const float* __restrict__ x,
                                                  unsigned short* __restrict__ gcb){
  int row = blockIdx.x;         // 0..127
  int t = threadIdx.x;
  unsigned short* dst = gcb + (size_t)row * DIM;
  if (row < BATCH * 32){
    int b = row >> 5, g = row & 31;
    const float* src = x + ((size_t)b * SEQ + (size_t)g * 64) * DIM;
    f4 v = *(const f4*)&src[t * 4];
    u16x4 o = { f2bf(v[0]), f2bf(v[1]), f2bf(v[2]), f2bf(v[3]) };
    *(u16x4*)&dst[t * 4] = o;
  } else {
    u16x4 z = { 0, 0, 0, 0 };
    *(u16x4*)&dst[t * 4] = z;
  }
}

// ---------------- multi-output bf16 MFMA GEMM ----------------
// C[:, wi*1024:(wi+1)*1024] goes to descriptor wi (independent dest/layout/bias).
// BN=128: 128x128 tile, 4 waves 2x2. BN=64: 128x64 tile (2 blocks/CU for N=1024 GEMMs).
// tr=1: write C^T via MFMA operand swap (epilogue stays coalesced).
// XCD-contiguous block swizzle: each XCD owns contiguous tile-rows -> A-panel L2 reuse.
struct GOut { unsigned short* ob; float* of; const float* bias; int ld; int tr; };
struct GOuts { GOut d[4]; };

template<int BN>
__global__ __launch_bounds__(256) void gemm_bf16(
    const unsigned short* __restrict__ A, const unsigned short* __restrict__ Bt,
    GOuts descs, int K)
{
  constexpr int NF = BN / 32;                 // n-frags per wave
  __shared__ __align__(16) unsigned short As[128 * 32];
  __shared__ __align__(16) unsigned short Bs[BN * 32];
  const int tid = threadIdx.x;
  const int lane = tid & 63;
  const int w = tid >> 6;
  const int wr = w >> 1, wc = w & 1;
  const int gx = gridDim.x;
  const int nwg = gx * gridDim.y;             // always % 8 == 0
  const int orig = blockIdx.y * gx + blockIdx.x;
  const int swz = (orig & 7) * (nwg >> 3) + (orig >> 3);
  const int tx = swz % gx, ty = swz / gx;
  const int tm = ty << 7, tn = tx * BN;
  const GOut dsc = descs.d[tn >> 10];
  const int trans = dsc.tr;

  const int r0 = tid >> 2;
  const int c0 = (tid & 3) << 3;
  const unsigned short* Ag0 = A + (size_t)(tm + r0) * K + c0;
  const unsigned short* Ag1 = A + (size_t)(tm + r0 + 64) * K + c0;
  const unsigned short* Bg0 = Bt + (size_t)(tn + r0) * K + c0;
  const unsigned short* Bg1 = Bt + (size_t)(tn + (BN == 128 ? r0 + 64 : r0)) * K + c0;
  unsigned short* AsW0 = &As[w * 512];
  unsigned short* AsW1 = &As[w * 512 + 2048];
  unsigned short* BsW0 = &Bs[w * 512];
  unsigned short* BsW1 = &Bs[(BN == 128 ? w * 512 + 2048 : w * 512)];

  f32x4 acc[4][NF];
  #pragma unroll
  for (int m = 0; m < 4; ++m)
    #pragma unroll
    for (int n = 0; n < NF; ++n) acc[m][n] = (f32x4){0.f, 0.f, 0.f, 0.f};

  const int fr = lane & 15, fg = lane >> 4;
  for (int kk = 0; kk < K; kk += 32){
    ASYNC_LDS16(Ag0 + kk, AsW0);
    ASYNC_LDS16(Ag1 + kk, AsW1);
    ASYNC_LDS16(Bg0 + kk, BsW0);
    if constexpr (BN == 128) ASYNC_LDS16(Bg1 + kk, BsW1);
    __syncthreads();
    s16x8 af[4], bfv[NF];
    #pragma unroll
    for (int m = 0; m < 4; ++m)
      af[m] = *(const s16x8*)&As[(wr * 64 + m * 16 + fr) * 32 + fg * 8];
    #pragma unroll
    for (int n = 0; n < NF; ++n)
      bfv[n] = *(const s16x8*)&Bs[(wc * (BN / 2) + n * 16 + fr) * 32 + fg * 8];
    if (trans){
      #pragma unroll
      for (int m = 0; m < 4; ++m)
        #pragma unroll
        for (int n = 0; n < NF; ++n)
          acc[m][n] = __builtin_amdgcn_mfma_f32_16x16x32_bf16(bfv[n], af[m], acc[m][n], 0, 0, 0);
    } else {
      #pragma unroll
      for (int m = 0; m < 4; ++m)
        #pragma unroll
        for (int n = 0; n < NF; ++n)
          acc[m][n] = __builtin_amdgcn_mfma_f32_16x16x32_bf16(af[m], bfv[n], acc[m][n], 0, 0, 0);
    }
    __syncthreads();
  }
  // epilogue
  #pragma unroll
  for (int m = 0; m < 4; ++m){
    #pragma unroll
    for (int n = 0; n < NF; ++n){
      if (!trans){
        int cl = (tn + wc * (BN / 2) + n * 16 + fr) & 1023;   // col within this output
        float bv = dsc.bias ? dsc.bias[cl] : 0.f;
        #pragma unroll
        for (int r = 0; r < 4; ++r){
          int row = tm + wr * 64 + m * 16 + fg * 4 + r;
          float v = acc[m][n][r] + bv;
          if (dsc.of) dsc.of[(size_t)row * dsc.ld + cl] = v;
          if (dsc.ob) dsc.ob[(size_t)row * dsc.ld + cl] = f2bf(v);
        }
      } else {
        int colT = tm + wr * 64 + m * 16 + fr;                // token
        #pragma unroll
        for (int r = 0; r < 4; ++r){
          int dl = (tn + wc * (BN / 2) + n * 16 + fg * 4 + r) & 1023;  // d_out within output
          float v = acc[m][n][r] + (dsc.bias ? dsc.bias[dl] : 0.f);
          dsc.ob[(size_t)dl * dsc.ld + colT] = f2bf(v);
        }
      }
    }
  }
}

// ---------------- unified MFMA flash attention ----------------
// MODE 0 = local window (256, block-diagonal), 1 = sliding band (|q-j|<=256), 2 = global (32 keys).
// Block = (b, qc, h): 64 q rows. 4 waves x 16 q. K/V tiles of 64 keys.
template<int MODE>
__global__ __launch_bounds__(256) void mfma_attn(
    const unsigned short* __restrict__ Qb,
    const unsigned short* __restrict__ Kb,
    const unsigned short* __restrict__ Vtb, int ldvt,
    unsigned short* __restrict__ Out, int ldo, int ocol)
{
  __shared__ __align__(16) unsigned short Ks[64][72];
  __shared__ __align__(16) unsigned short Vs[64][72];     // XOR-swizzled within rows
  __shared__ __align__(16) unsigned short Pl[4][16][72];  // per-wave P buffer
  const int tid = threadIdx.x, lane = tid & 63, wv = tid >> 6;
  const int fr = lane & 15, fg = lane >> 4;
  const int blk = blockIdx.x;              // b*512 + qc*16 + h
  const int h  = blk & 15;
  const int qc = (blk >> 4) & 31;
  const int b  = blk >> 9;
  const int q0 = qc * 64;                  // seq-local
  const int tq0 = b * SEQ + q0;            // token index
  int jlo, ntile;
  if (MODE == 0){ jlo = (qc >> 2) << 8; ntile = 4; }
  else if (MODE == 1){
    jlo = q0 - 256 < 0 ? 0 : q0 - 256;
    int jhi = q0 + 320 > SEQ ? SEQ : q0 + 320;
    ntile = (jhi - jlo) >> 6;
  } else { jlo = 0; ntile = 1; }
  const int ktok0 = (MODE == 2) ? b * 32 : b * SEQ;

  s16x8 qf[2];
  {
    const size_t qrow = (size_t)(tq0 + wv * 16 + fr) * DIM + h * DK;
    qf[0] = *(const s16x8*)&Qb[qrow + fg * 8];
    qf[1] = *(const s16x8*)&Qb[qrow + 32 + fg * 8];
  }
  f32x4 of[4];
  #pragma unroll
  for (int dt = 0; dt < 4; ++dt) of[dt] = (f32x4){0.f, 0.f, 0.f, 0.f};
  f32x4 m4 = (f32x4){MINIT, MINIT, MINIT, MINIT};
  f32x4 l4 = (f32x4){0.f, 0.f, 0.f, 0.f};

  for (int t = 0; t < ntile; ++t){
    const int jb = jlo + t * 64;
    __syncthreads();
    #pragma unroll
    for (int p = 0; p < 2; ++p){
      int idx = p * 256 + tid;
      int row = idx >> 3, c8 = idx & 7;
      *(i32x4*)&Ks[row][c8 * 8] =
          *(const i32x4*)&Kb[(size_t)(ktok0 + jb + row) * DIM + h * DK + c8 * 8];
      i32x4 v = *(const i32x4*)&Vtb[(size_t)(h * DK + row) * ldvt + ktok0 + jb + c8 * 8];
      *(i32x4*)((char*)Vs + row * 144 + ((c8 * 16) ^ ((row & 7) << 4))) = v;
    }
    __syncthreads();
    f32x4 sf[4];
    #pragma unroll
    for (int t16 = 0; t16 < 4; ++t16){
      sf[t16] = (f32x4){0.f, 0.f, 0.f, 0.f};
      #pragma unroll
      for (int ks = 0; ks < 2; ++ks){
        s16x8 kf = *(const s16x8*)&Ks[t16 * 16 + fr][ks * 32 + fg * 8];
        sf[t16] = __builtin_amdgcn_mfma_f32_16x16x32_bf16(qf[ks], kf, sf[t16], 0, 0, 0);
      }
    }
    #pragma unroll
    for (int t16 = 0; t16 < 4; ++t16){
      int j = jb + t16 * 16 + fr;
      #pragma unroll
      for (int r = 0; r < 4; ++r){
        float v = sf[t16][r] * SCALE_F;
        bool valid = true;
        if (MODE == 1){ int dq = (q0 + wv * 16 + fg * 4 + r) - j; valid = (dq <= 256) && (dq >= -256); }
        if (MODE == 2){ valid = j < 32; }
        sf[t16][r] = valid ? v : MASKED;
      }
    }
    f32x4 mx;
    #pragma unroll
    for (int r = 0; r < 4; ++r)
      mx[r] = fmaxf(fmaxf(sf[0][r], sf[1][r]), fmaxf(sf[2][r], sf[3][r]));
    #pragma unroll
    for (int off = 1; off < 16; off <<= 1){
      #pragma unroll
      for (int r = 0; r < 4; ++r) mx[r] = fmaxf(mx[r], __shfl_xor(mx[r], off));
    }
    f32x4 sc;
    #pragma unroll
    for (int r = 0; r < 4; ++r){
      float mn = fmaxf(m4[r], mx[r]);
      sc[r] = __expf(m4[r] - mn);
      m4[r] = mn;
    }
    f32x4 sm = (f32x4){0.f, 0.f, 0.f, 0.f};
    #pragma unroll
    for (int t16 = 0; t16 < 4; ++t16){
      #pragma unroll
      for (int r = 0; r < 4; ++r){
        float e = __expf(sf[t16][r] - m4[r]);
        sm[r] += e;
        Pl[wv][fg * 4 + r][t16 * 16 + fr] = f2bf(e);
      }
    }
    #pragma unroll
    for (int off = 1; off < 16; off <<= 1){
      #pragma unroll
      for (int r = 0; r < 4; ++r) sm[r] += __shfl_xor(sm[r], off);
    }
    #pragma unroll
    for (int r = 0; r < 4; ++r) l4[r] = l4[r] * sc[r] + sm[r];
    #pragma unroll
    for (int dt = 0; dt < 4; ++dt)
      #pragma unroll
      for (int r = 0; r < 4; ++r) of[dt][r] *= sc[r];
    #pragma unroll
    for (int ks2 = 0; ks2 < 2; ++ks2){
      s16x8 pa = *(const s16x8*)&Pl[wv][fr][ks2 * 32 + fg * 8];
      #pragma unroll
      for (int dt = 0; dt < 4; ++dt){
        int d = dt * 16 + fr;
        s16x8 vf = *(const s16x8*)((char*)Vs + d * 144 + ((ks2 * 64 + fg * 16) ^ ((d & 7) << 4)));
        of[dt] = __builtin_amdgcn_mfma_f32_16x16x32_bf16(pa, vf, of[dt], 0, 0, 0);
      }
    }
  }
  #pragma unroll
  for (int dt = 0; dt < 4; ++dt){
    #pragma unroll
    for (int r = 0; r < 4; ++r){
      float val = of[dt][r] / l4[r];
      int q = tq0 + wv * 16 + fg * 4 + r;
      Out[(size_t)q * ldo + ocol + h * DK + dt * 16 + fr] = f2bf(val);
    }
  }
}

// ---------------- fused residual + LayerNorm ----------------
__global__ __launch_bounds__(256) void ln_fused(
    const float* __restrict__ x, const float* __restrict__ dlt,
    const float* __restrict__ g, const float* __restrict__ bta,
    float* __restrict__ outf, unsigned short* __restrict__ outb, int ldo)
{
  const int row = blockIdx.x;
  const int t = threadIdx.x, lane = t & 63, wv = t >> 6;
  const float* xr = x + (size_t)row * DIM;
  const float* dr = dlt + (size_t)row * DIM;
  f4 xv = *(const f4*)&xr[t * 4];
  f4 dv = *(const f4*)&dr[t * 4];
  f4 y = xv + dv;
  float s = y[0] + y[1] + y[2] + y[3];
  float ss = y[0]*y[0] + y[1]*y[1] + y[2]*y[2] + y[3]*y[3];
  #pragma unroll
  for (int off = 1; off < 64; off <<= 1){ s += __shfl_xor(s, off); ss += __shfl_xor(ss, off); }
  __shared__ float red[8];
  if (lane == 0){ red[wv] = s; red[wv + 4] = ss; }
  __syncthreads();
  float S = red[0] + red[1] + red[2] + red[3];
  float SS = red[4] + red[5] + red[6] + red[7];
  float mu = S * (1.f / DIM);
  float var = SS * (1.f / DIM) - mu * mu;
  float rs = rsqrtf(var + 1e-5f);
  f4 gv = *(const f4*)&g[t * 4];
  f4 bv = *(const f4*)&bta[t * 4];
  f4 o;
  #pragma unroll
  for (int i = 0; i < 4; ++i) o[i] = (y[i] - mu) * rs * gv[i] + bv[i];
  if (outf) *(f4*)&outf[(size_t)row * ldo + t * 4] = o;
  if (outb){
    u16x4 ob = { f2bf(o[0]), f2bf(o[1]), f2bf(o[2]), f2bf(o[3]) };
    *(u16x4*)&outb[(size_t)row * ldo + t * 4] = ob;
  }
}

// ---------------- host launch ----------------
extern "C" void kernel_launch(void* const* d_in, const int* in_sizes, int n_in,
                              void* d_out, int out_size, void* d_ws, size_t ws_size,
                              hipStream_t stream){
  (void)in_sizes; (void)n_in; (void)out_size; (void)ws_size;
  const float* x      = (const float*)d_in[0];
  const float* lq_w   = (const float*)d_in[1];  const float* lq_b  = (const float*)d_in[2];
  const float* lk_w   = (const float*)d_in[3];  const float* lk_b  = (const float*)d_in[4];
  const float* lv_w   = (const float*)d_in[5];  const float* lv_b  = (const float*)d_in[6];
  const float* gq_w   = (const float*)d_in[7];  const float* gq_b  = (const float*)d_in[8];
  const float* gk_w   = (const float*)d_in[9];  const float* gk_b  = (const float*)d_in[10];
  const float* gv_w   = (const float*)d_in[11]; const float* gv_b  = (const float*)d_in[12];
  const float* ho_w   = (const float*)d_in[13]; const float* ho_b  = (const float*)d_in[14];
  const float* hln_g  = (const float*)d_in[15]; const float* hln_b = (const float*)d_in[16];
  const float* sq_w   = (const float*)d_in[17]; const float* sq_b  = (const float*)d_in[18];
  const float* sk_w   = (const float*)d_in[19]; const float* sk_b  = (const float*)d_in[20];
  const float* sv_w   = (const float*)d_in[21]; const float* sv_b  = (const float*)d_in[22];
  const float* so_w   = (const float*)d_in[23]; const float* so_b  = (const float*)d_in[24];
  const float* cb_w   = (const float*)d_in[25]; const float* cb_b  = (const float*)d_in[26];
  const float* ln_g   = (const float*)d_in[27]; const float* ln_b  = (const float*)d_in[28];

  const size_t M = (size_t)BATCH * SEQ;      // 4096
  const size_t W1 = (size_t)DIM * DIM;       // one 1024x1024 weight (elements)
  char* ws = (char*)d_ws;
  size_t off = 0;
  auto alloc = [&](size_t bytes) -> void* {
    void* p = ws + off; off += (bytes + 255) & ~(size_t)255; return p;
  };
  unsigned short* xb    = (unsigned short*)alloc(M * DIM * 2);
  unsigned short* wt_s  = (unsigned short*)alloc(3 * W1 * 2);   // [sq|sk|sv]
  unsigned short* wt_lg = (unsigned short*)alloc(4 * W1 * 2);   // [lq|lk|lv|gq]
  unsigned short* wt_g2 = (unsigned short*)alloc(2 * W1 * 2);   // [gk|gv]
  unsigned short* wt_so = (unsigned short*)alloc(W1 * 2);
  unsigned short* wt_ho = (unsigned short*)alloc(2 * W1 * 2);
  unsigned short* wt_cb = (unsigned short*)alloc(2 * W1 * 2);
  unsigned short* gcb   = (unsigned short*)alloc((size_t)128 * DIM * 2);
  unsigned short* qb    = (unsigned short*)alloc(M * DIM * 2);
  unsigned short* kb    = (unsigned short*)alloc(M * DIM * 2);
  unsigned short* vtb   = (unsigned short*)alloc(M * DIM * 2);   // [1024][4096]
  unsigned short* qg    = (unsigned short*)alloc(M * DIM * 2);
  unsigned short* gkb   = (unsigned short*)alloc((size_t)128 * DIM * 2);
  unsigned short* vtg   = (unsigned short*)alloc((size_t)128 * DIM * 2); // [1024][128]
  unsigned short* satt  = (unsigned short*)alloc(M * DIM * 2);
  unsigned short* hcat  = (unsigned short*)alloc(M * 2 * DIM * 2);
  unsigned short* ccat  = (unsigned short*)alloc(M * 2 * DIM * 2);
  float* Af             = (float*)alloc(M * DIM * 4);

  dim3 b256(256);
  // ---- casts / transposes ----
  cast_bf16_kernel<<<dim3((M * DIM) / 1024), b256, 0, stream>>>(x, xb, (int)(M * DIM));
  {
    TCP p1 = {};
    const float* ws_[10] = {sq_w, sk_w, sv_w, lq_w, lk_w, lv_w, gq_w, gk_w, gv_w, so_w};
    unsigned short* wts_[10] = {wt_s, wt_s + W1, wt_s + 2 * W1,
                                wt_lg, wt_lg + W1, wt_lg + 2 * W1, wt_lg + 3 * W1,
                                wt_g2, wt_g2 + W1, wt_so};
    for (int i = 0; i < 10; ++i){ p1.w[i] = ws_[i]; p1.wt[i] = wts_[i]; }
    transpose_cast_b<<<dim3(32, 32, 10), b256, 0, stream>>>(p1, DIM);
    TCP p2 = {};
    p2.w[0] = ho_w; p2.wt[0] = wt_ho;
    p2.w[1] = cb_w; p2.wt[1] = wt_cb;
    transpose_cast_b<<<dim3(32, 64, 2), b256, 0, stream>>>(p2, 2 * DIM);
  }
  gc_extract<<<dim3(128), b256, 0, stream>>>(x, gcb);

  dim3 attn_grid(1024);
  auto mk = [&](unsigned short* ob, float* of, const float* bias, int ld, int tr) -> GOut {
    GOut g; g.ob = ob; g.of = of; g.bias = bias; g.ld = ld; g.tr = tr; return g;
  };

  // ---- sliding branch: fused QKV (N=3072, 768 blocks = 3/CU) ----
  {
    GOuts ds = {};
    ds.d[0] = mk(qb,  nullptr, sq_b, DIM, 0);
    ds.d[1] = mk(kb,  nullptr, sk_b, DIM, 0);
    ds.d[2] = mk(vtb, nullptr, sv_b, (int)M, 1);
    gemm_bf16<128><<<dim3(24, 32), b256, 0, stream>>>(xb, wt_s, ds, DIM);
  }
  mfma_attn<1><<<attn_grid, b256, 0, stream>>>(qb, kb, vtb, (int)M, satt, DIM, 0);

  // ---- local + gq: fused (N=4096, 1024 blocks = 4/CU) ----
  {
    GOuts ds = {};
    ds.d[0] = mk(qb,  nullptr, lq_b, DIM, 0);
    ds.d[1] = mk(kb,  nullptr, lk_b, DIM, 0);
    ds.d[2] = mk(vtb, nullptr, lv_b, (int)M, 1);
    ds.d[3] = mk(qg,  nullptr, gq_b, DIM, 0);
    gemm_bf16<128><<<dim3(32, 32), b256, 0, stream>>>(xb, wt_lg, ds, DIM);
  }
  // ---- s_out projection (N=1024, BN=64 -> 512 blocks = 2/CU) ----
  {
    GOuts ds = {};
    ds.d[0] = mk(ccat + 1024, nullptr, so_b, 2 * DIM, 0);
    gemm_bf16<64><<<dim3(16, 32), b256, 0, stream>>>(satt, wt_so, ds, DIM);
  }
  mfma_attn<0><<<attn_grid, b256, 0, stream>>>(qb, kb, vtb, (int)M, hcat, 2 * DIM, 0);

  // ---- global branch: fused gk+gv (M=128, N=2048) ----
  {
    GOuts ds = {};
    ds.d[0] = mk(gkb, nullptr, gk_b, DIM, 0);
    ds.d[1] = mk(vtg, nullptr, gv_b, 128, 1);
    gemm_bf16<128><<<dim3(16, 1), b256, 0, stream>>>(gcb, wt_g2, ds, DIM);
  }
  mfma_attn<2><<<attn_grid, b256, 0, stream>>>(qg, gkb, vtg, 128, hcat, 2 * DIM, 1024);

  // ---- h_out projection + LN1 ----
  {
    GOuts ds = {};
    ds.d[0] = mk(nullptr, Af, ho_b, DIM, 0);
    gemm_bf16<64><<<dim3(16, 32), b256, 0, stream>>>(hcat, wt_ho, ds, 2 * DIM);
  }
  ln_fused<<<dim3((int)M), b256, 0, stream>>>(x, Af, hln_g, hln_b, nullptr, ccat, 2 * DIM);

  // ---- combine + LN2 ----
  {
    GOuts ds = {};
    ds.d[0] = mk(nullptr, Af, cb_b, DIM, 0);
    gemm_bf16<64><<<dim3(16, 32), b256, 0, stream>>>(ccat, wt_cb, ds, 2 * DIM);
  }
  ln_fused<<<dim3((int)M), b256, 0, stream>>>(x, Af, ln_g, ln_b, (float*)d_out, nullptr, DIM);
}

// Round 5
// 525.227 us; speedup vs baseline: 2.1572x; 1.0761x over previous
//
#include <hip/hip_runtime.h>

// ---------------- problem constants ----------------
#define BATCH 2
#define SEQ   2048
#define DIM   1024
#define NH    16
#define DK    64
#define SCALE_F 0.125f
#define MASKED  -2e30f
#define MINIT   -1e30f

typedef __attribute__((ext_vector_type(4))) float f4;
typedef __attribute__((ext_vector_type(4))) float f32x4;
typedef __attribute__((ext_vector_type(8))) short s16x8;
typedef __attribute__((ext_vector_type(4))) int  i32x4;
typedef __attribute__((ext_vector_type(4))) unsigned short u16x4;

__device__ __forceinline__ float bf2f(unsigned short u){ return __uint_as_float(((unsigned)u) << 16); }
__device__ __forceinline__ unsigned short f2bf(float f){
  unsigned u = __float_as_uint(f);
  u += 0x7FFFu + ((u >> 16) & 1u);
  return (unsigned short)(u >> 16);
}

// async global->LDS, 16B per lane. LDS dest = wave-uniform base + lane*16.
#define ASYNC_LDS16(g, l) \
  __builtin_amdgcn_global_load_lds((const __attribute__((address_space(1))) void*)(g), \
                                   (__attribute__((address_space(3))) void*)(l), 16, 0, 0)

// ---------------- cast fp32 -> bf16 (vectorized) ----------------
__global__ __launch_bounds__(256) void cast_bf16_kernel(const float* __restrict__ in,
                                                        unsigned short* __restrict__ out, int n){
  int i = (blockIdx.x * 256 + threadIdx.x) * 4;
  if (i < n){
    f4 v = *(const f4*)&in[i];
    u16x4 o = { f2bf(v[0]), f2bf(v[1]), f2bf(v[2]), f2bf(v[3]) };
    *(u16x4*)&out[i] = o;
  }
}

// ---------------- batched transpose + cast: W (K x DIM fp32) -> Wt (DIM x K bf16) ----------------
struct TCP { const float* w[12]; unsigned short* wt[12]; };
__global__ __launch_bounds__(256) void transpose_cast_b(TCP P, int K){
  const float* W = P.w[blockIdx.z];
  unsigned short* Wt = P.wt[blockIdx.z];
  __shared__ float tile[32][33];
  int x = threadIdx.x & 31, y = threadIdx.x >> 5;
  int bc = blockIdx.x << 5;   // over N (=DIM)
  int br = blockIdx.y << 5;   // over K
  #pragma unroll
  for (int yy = y; yy < 32; yy += 8)
    tile[yy][x] = W[(size_t)(br + yy) * DIM + bc + x];
  __syncthreads();
  #pragma unroll
  for (int yy = y; yy < 32; yy += 8)
    Wt[(size_t)(bc + yy) * K + br + x] = f2bf(tile[x][yy]);
}

// ---------------- gc extraction: x[:, ::64] -> bf16, padded to 128 rows ----------------
__global__ __launch_bounds__(256) void gc_extract(const float* __restrict__ x,
                                                  unsigned short* __restrict__ gcb){
  int row = blockIdx.x;         // 0..127
  int t = threadIdx.x;
  unsigned short* dst = gcb + (size_t)row * DIM;
  if (row < BATCH * 32){
    int b = row >> 5, g = row & 31;
    const float* src = x + ((size_t)b * SEQ + (size_t)g * 64) * DIM;
    f4 v = *(const f4*)&src[t * 4];
    u16x4 o = { f2bf(v[0]), f2bf(v[1]), f2bf(v[2]), f2bf(v[3]) };
    *(u16x4*)&dst[t * 4] = o;
  } else {
    u16x4 z = { 0, 0, 0, 0 };
    *(u16x4*)&dst[t * 4] = z;
  }
}

// ---------------- multi-output bf16 MFMA GEMM ----------------
// C[:, wi*1024:(wi+1)*1024] goes to descriptor wi (independent dest/layout/bias).
// Pipeline: LDS double-buffer, counted vmcnt (never drained in-loop), raw s_barrier.
// LDS k-chunk XOR swizzle via pre-swizzled GLOBAL source + swizzled ds_read (rule #21):
//   phys chunk p at row R holds logical chunk p ^ ((R>>1)&3)  -> 2-way banks (free).
// tr=1: write C^T via MFMA operand swap. XCD-contiguous block swizzle for L2 reuse.
struct GOut { unsigned short* ob; float* of; const float* bias; int ld; int tr; };
struct GOuts { GOut d[4]; };

template<int BN>
__global__ __launch_bounds__(256) void gemm_bf16(
    const unsigned short* __restrict__ A, const unsigned short* __restrict__ Bt,
    GOuts descs, int K)
{
  constexpr int NF = BN / 32;                 // n-frags per wave
  __shared__ __align__(16) unsigned short As[2][128 * 32];
  __shared__ __align__(16) unsigned short Bs[2][BN * 32];
  const int tid = threadIdx.x;
  const int lane = tid & 63;
  const int w = tid >> 6;
  const int wr = w >> 1, wc = w & 1;
  const int gx = gridDim.x;
  const int nwg = gx * gridDim.y;             // always % 8 == 0
  const int orig = blockIdx.y * gx + blockIdx.x;
  const int swz = (orig & 7) * (nwg >> 3) + (orig >> 3);
  const int tx = swz % gx, ty = swz / gx;
  const int tm = ty << 7, tn = tx * BN;
  const GOut dsc = descs.d[tn >> 10];
  const int trans = dsc.tr;

  const int r0 = tid >> 2;
  const int ksw = (((tid & 3) ^ ((tid >> 3) & 3)) << 3);   // pre-swizzled k-offset (elems)
  const unsigned short* Ag0 = A + (size_t)(tm + r0) * K + ksw;
  const unsigned short* Ag1 = A + (size_t)(tm + r0 + 64) * K + ksw;
  const unsigned short* Bg0 = Bt + (size_t)(tn + r0) * K + ksw;
  const unsigned short* Bg1 = Bt + (size_t)(tn + r0 + 64) * K + ksw;  // BN==128 only

  f32x4 acc[4][NF];
  #pragma unroll
  for (int m = 0; m < 4; ++m)
    #pragma unroll
    for (int n = 0; n < NF; ++n) acc[m][n] = (f32x4){0.f, 0.f, 0.f, 0.f};

  const int fr = lane & 15, fg = lane >> 4;
  const int kro = ((fg ^ ((fr >> 1) & 3)) << 3);           // swizzled read chunk (elems)

  auto STAGE = [&](int buf, int t){
    const int kk = t * 32;
    ASYNC_LDS16(Ag0 + kk, &As[buf][w * 512]);
    ASYNC_LDS16(Ag1 + kk, &As[buf][w * 512 + 2048]);
    ASYNC_LDS16(Bg0 + kk, &Bs[buf][w * 512]);
    if constexpr (BN == 128) ASYNC_LDS16(Bg1 + kk, &Bs[buf][w * 512 + 2048]);
  };
  auto COMPUTE = [&](int buf){
    s16x8 af[4], bfv[NF];
    #pragma unroll
    for (int m = 0; m < 4; ++m)
      af[m] = *(const s16x8*)&As[buf][(wr * 64 + m * 16 + fr) * 32 + kro];
    #pragma unroll
    for (int n = 0; n < NF; ++n)
      bfv[n] = *(const s16x8*)&Bs[buf][(wc * (BN / 2) + n * 16 + fr) * 32 + kro];
    if (trans){
      #pragma unroll
      for (int m = 0; m < 4; ++m)
        #pragma unroll
        for (int n = 0; n < NF; ++n)
          acc[m][n] = __builtin_amdgcn_mfma_f32_16x16x32_bf16(bfv[n], af[m], acc[m][n], 0, 0, 0);
    } else {
      #pragma unroll
      for (int m = 0; m < 4; ++m)
        #pragma unroll
        for (int n = 0; n < NF; ++n)
          acc[m][n] = __builtin_amdgcn_mfma_f32_16x16x32_bf16(af[m], bfv[n], acc[m][n], 0, 0, 0);
    }
  };

  const int nt = K >> 5;                       // K/32 tiles, always >= 2
  STAGE(0, 0);
  STAGE(1, 1);
  for (int t = 0; t < nt - 1; ++t){
    const int cur = t & 1;
    if constexpr (BN == 128) asm volatile("s_waitcnt vmcnt(4)" ::: "memory");
    else                     asm volatile("s_waitcnt vmcnt(3)" ::: "memory");
    __builtin_amdgcn_s_barrier();
    __builtin_amdgcn_sched_barrier(0);        // no ds_read above the barrier
    COMPUTE(cur);
    __builtin_amdgcn_sched_barrier(0);        // MFMA/ds_read stay before barrier
    __builtin_amdgcn_s_barrier();
    __builtin_amdgcn_sched_barrier(0);        // no stage-write above the barrier
    if (t + 2 < nt) STAGE(cur, t + 2);
  }
  asm volatile("s_waitcnt vmcnt(0)" ::: "memory");
  __builtin_amdgcn_s_barrier();
  __builtin_amdgcn_sched_barrier(0);
  COMPUTE((nt - 1) & 1);

  // epilogue
  #pragma unroll
  for (int m = 0; m < 4; ++m){
    #pragma unroll
    for (int n = 0; n < NF; ++n){
      if (!trans){
        int cl = (tn + wc * (BN / 2) + n * 16 + fr) & 1023;   // col within this output
        float bv = dsc.bias ? dsc.bias[cl] : 0.f;
        #pragma unroll
        for (int r = 0; r < 4; ++r){
          int row = tm + wr * 64 + m * 16 + fg * 4 + r;
          float v = acc[m][n][r] + bv;
          if (dsc.of) dsc.of[(size_t)row * dsc.ld + cl] = v;
          if (dsc.ob) dsc.ob[(size_t)row * dsc.ld + cl] = f2bf(v);
        }
      } else {
        int colT = tm + wr * 64 + m * 16 + fr;                // token
        #pragma unroll
        for (int r = 0; r < 4; ++r){
          int dl = (tn + wc * (BN / 2) + n * 16 + fg * 4 + r) & 1023;  // d_out within output
          float v = acc[m][n][r] + (dsc.bias ? dsc.bias[dl] : 0.f);
          dsc.ob[(size_t)dl * dsc.ld + colT] = f2bf(v);
        }
      }
    }
  }
}

// ---------------- unified MFMA flash attention ----------------
// MODE 0 = local window (256, block-diagonal), 1 = sliding band (|q-j|<=256), 2 = global (32 keys).
// Block = (b, qc, h): 64 q rows. 4 waves x 16 q. K/V tiles of 64 keys.
template<int MODE>
__global__ __launch_bounds__(256) void mfma_attn(
    const unsigned short* __restrict__ Qb,
    const unsigned short* __restrict__ Kb,
    const unsigned short* __restrict__ Vtb, int ldvt,
    unsigned short* __restrict__ Out, int ldo, int ocol)
{
  __shared__ __align__(16) unsigned short Ks[64][72];
  __shared__ __align__(16) unsigned short Vs[64][72];     // XOR-swizzled within rows
  __shared__ __align__(16) unsigned short Pl[4][16][72];  // per-wave P buffer
  const int tid = threadIdx.x, lane = tid & 63, wv = tid >> 6;
  const int fr = lane & 15, fg = lane >> 4;
  const int blk = blockIdx.x;              // b*512 + qc*16 + h
  const int h  = blk & 15;
  const int qc = (blk >> 4) & 31;
  const int b  = blk >> 9;
  const int q0 = qc * 64;                  // seq-local
  const int tq0 = b * SEQ + q0;            // token index
  int jlo, ntile;
  if (MODE == 0){ jlo = (qc >> 2) << 8; ntile = 4; }
  else if (MODE == 1){
    jlo = q0 - 256 < 0 ? 0 : q0 - 256;
    int jhi = q0 + 320 > SEQ ? SEQ : q0 + 320;
    ntile = (jhi - jlo) >> 6;
  } else { jlo = 0; ntile = 1; }
  const int ktok0 = (MODE == 2) ? b * 32 : b * SEQ;

  s16x8 qf[2];
  {
    const size_t qrow = (size_t)(tq0 + wv * 16 + fr) * DIM + h * DK;
    qf[0] = *(const s16x8*)&Qb[qrow + fg * 8];
    qf[1] = *(const s16x8*)&Qb[qrow + 32 + fg * 8];
  }
  f32x4 of[4];
  #pragma unroll
  for (int dt = 0; dt < 4; ++dt) of[dt] = (f32x4){0.f, 0.f, 0.f, 0.f};
  f32x4 m4 = (f32x4){MINIT, MINIT, MINIT, MINIT};
  f32x4 l4 = (f32x4){0.f, 0.f, 0.f, 0.f};

  for (int t = 0; t < ntile; ++t){
    const int jb = jlo + t * 64;
    __syncthreads();
    #pragma unroll
    for (int p = 0; p < 2; ++p){
      int idx = p * 256 + tid;
      int row = idx >> 3, c8 = idx & 7;
      *(i32x4*)&Ks[row][c8 * 8] =
          *(const i32x4*)&Kb[(size_t)(ktok0 + jb + row) * DIM + h * DK + c8 * 8];
      i32x4 v = *(const i32x4*)&Vtb[(size_t)(h * DK + row) * ldvt + ktok0 + jb + c8 * 8];
      *(i32x4*)((char*)Vs + row * 144 + ((c8 * 16) ^ ((row & 7) << 4))) = v;
    }
    __syncthreads();
    f32x4 sf[4];
    #pragma unroll
    for (int t16 = 0; t16 < 4; ++t16){
      sf[t16] = (f32x4){0.f, 0.f, 0.f, 0.f};
      #pragma unroll
      for (int ks = 0; ks < 2; ++ks){
        s16x8 kf = *(const s16x8*)&Ks[t16 * 16 + fr][ks * 32 + fg * 8];
        sf[t16] = __builtin_amdgcn_mfma_f32_16x16x32_bf16(qf[ks], kf, sf[t16], 0, 0, 0);
      }
    }
    #pragma unroll
    for (int t16 = 0; t16 < 4; ++t16){
      int j = jb + t16 * 16 + fr;
      #pragma unroll
      for (int r = 0; r < 4; ++r){
        float v = sf[t16][r] * SCALE_F;
        bool valid = true;
        if (MODE == 1){ int dq = (q0 + wv * 16 + fg * 4 + r) - j; valid = (dq <= 256) && (dq >= -256); }
        if (MODE == 2){ valid = j < 32; }
        sf[t16][r] = valid ? v : MASKED;
      }
    }
    f32x4 mx;
    #pragma unroll
    for (int r = 0; r < 4; ++r)
      mx[r] = fmaxf(fmaxf(sf[0][r], sf[1][r]), fmaxf(sf[2][r], sf[3][r]));
    #pragma unroll
    for (int off = 1; off < 16; off <<= 1){
      #pragma unroll
      for (int r = 0; r < 4; ++r) mx[r] = fmaxf(mx[r], __shfl_xor(mx[r], off));
    }
    f32x4 sc;
    #pragma unroll
    for (int r = 0; r < 4; ++r){
      float mn = fmaxf(m4[r], mx[r]);
      sc[r] = __expf(m4[r] - mn);
      m4[r] = mn;
    }
    f32x4 sm = (f32x4){0.f, 0.f, 0.f, 0.f};
    #pragma unroll
    for (int t16 = 0; t16 < 4; ++t16){
      #pragma unroll
      for (int r = 0; r < 4; ++r){
        float e = __expf(sf[t16][r] - m4[r]);
        sm[r] += e;
        Pl[wv][fg * 4 + r][t16 * 16 + fr] = f2bf(e);
      }
    }
    #pragma unroll
    for (int off = 1; off < 16; off <<= 1){
      #pragma unroll
      for (int r = 0; r < 4; ++r) sm[r] += __shfl_xor(sm[r], off);
    }
    #pragma unroll
    for (int r = 0; r < 4; ++r) l4[r] = l4[r] * sc[r] + sm[r];
    #pragma unroll
    for (int dt = 0; dt < 4; ++dt)
      #pragma unroll
      for (int r = 0; r < 4; ++r) of[dt][r] *= sc[r];
    #pragma unroll
    for (int ks2 = 0; ks2 < 2; ++ks2){
      s16x8 pa = *(const s16x8*)&Pl[wv][fr][ks2 * 32 + fg * 8];
      #pragma unroll
      for (int dt = 0; dt < 4; ++dt){
        int d = dt * 16 + fr;
        s16x8 vf = *(const s16x8*)((char*)Vs + d * 144 + ((ks2 * 64 + fg * 16) ^ ((d & 7) << 4)));
        of[dt] = __builtin_amdgcn_mfma_f32_16x16x32_bf16(pa, vf, of[dt], 0, 0, 0);
      }
    }
  }
  #pragma unroll
  for (int dt = 0; dt < 4; ++dt){
    #pragma unroll
    for (int r = 0; r < 4; ++r){
      float val = of[dt][r] / l4[r];
      int q = tq0 + wv * 16 + fg * 4 + r;
      Out[(size_t)q * ldo + ocol + h * DK + dt * 16 + fr] = f2bf(val);
    }
  }
}

// ---------------- fused residual + LayerNorm ----------------
__global__ __launch_bounds__(256) void ln_fused(
    const float* __restrict__ x, const float* __restrict__ dlt,
    const float* __restrict__ g, const float* __restrict__ bta,
    float* __restrict__ outf, unsigned short* __restrict__ outb, int ldo)
{
  const int row = blockIdx.x;
  const int t = threadIdx.x, lane = t & 63, wv = t >> 6;
  const float* xr = x + (size_t)row * DIM;
  const float* dr = dlt + (size_t)row * DIM;
  f4 xv = *(const f4*)&xr[t * 4];
  f4 dv = *(const f4*)&dr[t * 4];
  f4 y = xv + dv;
  float s = y[0] + y[1] + y[2] + y[3];
  float ss = y[0]*y[0] + y[1]*y[1] + y[2]*y[2] + y[3]*y[3];
  #pragma unroll
  for (int off = 1; off < 64; off <<= 1){ s += __shfl_xor(s, off); ss += __shfl_xor(ss, off); }
  __shared__ float red[8];
  if (lane == 0){ red[wv] = s; red[wv + 4] = ss; }
  __syncthreads();
  float S = red[0] + red[1] + red[2] + red[3];
  float SS = red[4] + red[5] + red[6] + red[7];
  float mu = S * (1.f / DIM);
  float var = SS * (1.f / DIM) - mu * mu;
  float rs = rsqrtf(var + 1e-5f);
  f4 gv = *(const f4*)&g[t * 4];
  f4 bv = *(const f4*)&bta[t * 4];
  f4 o;
  #pragma unroll
  for (int i = 0; i < 4; ++i) o[i] = (y[i] - mu) * rs * gv[i] + bv[i];
  if (outf) *(f4*)&outf[(size_t)row * ldo + t * 4] = o;
  if (outb){
    u16x4 ob = { f2bf(o[0]), f2bf(o[1]), f2bf(o[2]), f2bf(o[3]) };
    *(u16x4*)&outb[(size_t)row * ldo + t * 4] = ob;
  }
}

// ---------------- host launch ----------------
extern "C" void kernel_launch(void* const* d_in, const int* in_sizes, int n_in,
                              void* d_out, int out_size, void* d_ws, size_t ws_size,
                              hipStream_t stream){
  (void)in_sizes; (void)n_in; (void)out_size; (void)ws_size;
  const float* x      = (const float*)d_in[0];
  const float* lq_w   = (const float*)d_in[1];  const float* lq_b  = (const float*)d_in[2];
  const float* lk_w   = (const float*)d_in[3];  const float* lk_b  = (const float*)d_in[4];
  const float* lv_w   = (const float*)d_in[5];  const float* lv_b  = (const float*)d_in[6];
  const float* gq_w   = (const float*)d_in[7];  const float* gq_b  = (const float*)d_in[8];
  const float* gk_w   = (const float*)d_in[9];  const float* gk_b  = (const float*)d_in[10];
  const float* gv_w   = (const float*)d_in[11]; const float* gv_b  = (const float*)d_in[12];
  const float* ho_w   = (const float*)d_in[13]; const float* ho_b  = (const float*)d_in[14];
  const float* hln_g  = (const float*)d_in[15]; const float* hln_b = (const float*)d_in[16];
  const float* sq_w   = (const float*)d_in[17]; const float* sq_b  = (const float*)d_in[18];
  const float* sk_w   = (const float*)d_in[19]; const float* sk_b  = (const float*)d_in[20];
  const float* sv_w   = (const float*)d_in[21]; const float* sv_b  = (const float*)d_in[22];
  const float* so_w   = (const float*)d_in[23]; const float* so_b  = (const float*)d_in[24];
  const float* cb_w   = (const float*)d_in[25]; const float* cb_b  = (const float*)d_in[26];
  const float* ln_g   = (const float*)d_in[27]; const float* ln_b  = (const float*)d_in[28];

  const size_t M = (size_t)BATCH * SEQ;      // 4096
  const size_t W1 = (size_t)DIM * DIM;       // one 1024x1024 weight (elements)
  char* ws = (char*)d_ws;
  size_t off = 0;
  auto alloc = [&](size_t bytes) -> void* {
    void* p = ws + off; off += (bytes + 255) & ~(size_t)255; return p;
  };
  unsigned short* xb    = (unsigned short*)alloc(M * DIM * 2);
  unsigned short* wt_s  = (unsigned short*)alloc(3 * W1 * 2);   // [sq|sk|sv]
  unsigned short* wt_lg = (unsigned short*)alloc(4 * W1 * 2);   // [lq|lk|lv|gq]
  unsigned short* wt_g2 = (unsigned short*)alloc(2 * W1 * 2);   // [gk|gv]
  unsigned short* wt_so = (unsigned short*)alloc(W1 * 2);
  unsigned short* wt_ho = (unsigned short*)alloc(2 * W1 * 2);
  unsigned short* wt_cb = (unsigned short*)alloc(2 * W1 * 2);
  unsigned short* gcb   = (unsigned short*)alloc((size_t)128 * DIM * 2);
  unsigned short* qb    = (unsigned short*)alloc(M * DIM * 2);
  unsigned short* kb    = (unsigned short*)alloc(M * DIM * 2);
  unsigned short* vtb   = (unsigned short*)alloc(M * DIM * 2);   // [1024][4096]
  unsigned short* qg    = (unsigned short*)alloc(M * DIM * 2);
  unsigned short* gkb   = (unsigned short*)alloc((size_t)128 * DIM * 2);
  unsigned short* vtg   = (unsigned short*)alloc((size_t)128 * DIM * 2); // [1024][128]
  unsigned short* satt  = (unsigned short*)alloc(M * DIM * 2);
  unsigned short* hcat  = (unsigned short*)alloc(M * 2 * DIM * 2);
  unsigned short* ccat  = (unsigned short*)alloc(M * 2 * DIM * 2);
  float* Af             = (float*)alloc(M * DIM * 4);

  dim3 b256(256);
  // ---- casts / transposes ----
  cast_bf16_kernel<<<dim3((M * DIM) / 1024), b256, 0, stream>>>(x, xb, (int)(M * DIM));
  {
    TCP p1 = {};
    const float* ws_[10] = {sq_w, sk_w, sv_w, lq_w, lk_w, lv_w, gq_w, gk_w, gv_w, so_w};
    unsigned short* wts_[10] = {wt_s, wt_s + W1, wt_s + 2 * W1,
                                wt_lg, wt_lg + W1, wt_lg + 2 * W1, wt_lg + 3 * W1,
                                wt_g2, wt_g2 + W1, wt_so};
    for (int i = 0; i < 10; ++i){ p1.w[i] = ws_[i]; p1.wt[i] = wts_[i]; }
    transpose_cast_b<<<dim3(32, 32, 10), b256, 0, stream>>>(p1, DIM);
    TCP p2 = {};
    p2.w[0] = ho_w; p2.wt[0] = wt_ho;
    p2.w[1] = cb_w; p2.wt[1] = wt_cb;
    transpose_cast_b<<<dim3(32, 64, 2), b256, 0, stream>>>(p2, 2 * DIM);
  }
  gc_extract<<<dim3(128), b256, 0, stream>>>(x, gcb);

  dim3 attn_grid(1024);
  auto mk = [&](unsigned short* ob, float* of, const float* bias, int ld, int tr) -> GOut {
    GOut g; g.ob = ob; g.of = of; g.bias = bias; g.ld = ld; g.tr = tr; return g;
  };

  // ---- sliding branch: fused QKV (N=3072, 768 blocks = 3/CU) ----
  {
    GOuts ds = {};
    ds.d[0] = mk(qb,  nullptr, sq_b, DIM, 0);
    ds.d[1] = mk(kb,  nullptr, sk_b, DIM, 0);
    ds.d[2] = mk(vtb, nullptr, sv_b, (int)M, 1);
    gemm_bf16<128><<<dim3(24, 32), b256, 0, stream>>>(xb, wt_s, ds, DIM);
  }
  mfma_attn<1><<<attn_grid, b256, 0, stream>>>(qb, kb, vtb, (int)M, satt, DIM, 0);

  // ---- local + gq: fused (N=4096, 1024 blocks = 4/CU) ----
  {
    GOuts ds = {};
    ds.d[0] = mk(qb,  nullptr, lq_b, DIM, 0);
    ds.d[1] = mk(kb,  nullptr, lk_b, DIM, 0);
    ds.d[2] = mk(vtb, nullptr, lv_b, (int)M, 1);
    ds.d[3] = mk(qg,  nullptr, gq_b, DIM, 0);
    gemm_bf16<128><<<dim3(32, 32), b256, 0, stream>>>(xb, wt_lg, ds, DIM);
  }
  // ---- s_out projection (N=1024, BN=64 -> 512 blocks = 2/CU) ----
  {
    GOuts ds = {};
    ds.d[0] = mk(ccat + 1024, nullptr, so_b, 2 * DIM, 0);
    gemm_bf16<64><<<dim3(16, 32), b256, 0, stream>>>(satt, wt_so, ds, DIM);
  }
  mfma_attn<0><<<attn_grid, b256, 0, stream>>>(qb, kb, vtb, (int)M, hcat, 2 * DIM, 0);

  // ---- global branch: fused gk+gv (M=128, N=2048) ----
  {
    GOuts ds = {};
    ds.d[0] = mk(gkb, nullptr, gk_b, DIM, 0);
    ds.d[1] = mk(vtg, nullptr, gv_b, 128, 1);
    gemm_bf16<128><<<dim3(16, 1), b256, 0, stream>>>(gcb, wt_g2, ds, DIM);
  }
  mfma_attn<2><<<attn_grid, b256, 0, stream>>>(qg, gkb, vtg, 128, hcat, 2 * DIM, 1024);

  // ---- h_out projection + LN1 ----
  {
    GOuts ds = {};
    ds.d[0] = mk(nullptr, Af, ho_b, DIM, 0);
    gemm_bf16<64><<<dim3(16, 32), b256, 0, stream>>>(hcat, wt_ho, ds, 2 * DIM);
  }
  ln_fused<<<dim3((int)M), b256, 0, stream>>>(x, Af, hln_g, hln_b, nullptr, ccat, 2 * DIM);

  // ---- combine + LN2 ----
  {
    GOuts ds = {};
    ds.d[0] = mk(nullptr, Af, cb_b, DIM, 0);
    gemm_bf16<64><<<dim3(16, 32), b256, 0, stream>>>(ccat, wt_cb, ds, 2 * DIM);
  }
  ln_fused<<<dim3((int)M), b256, 0, stream>>>(x, Af, ln_g, ln_b, (float*)d_out, nullptr, DIM);
}